// Round 8
// baseline (3696.366 us; speedup 1.0000x reference)
//
#include <hip/hip_runtime.h>
#include <hip/hip_bf16.h>

// ---------------------------------------------------------------------------
// RSSM scan on MI355X — round 8: shrink the L2 weight stream (port-bound).
// 64 blocks x 1024 thr (16 waves, 4/SIMD), RPB=16.
// r7 analysis: per-CU L2 streaming rate ~30 B/cy is the roofline; 1.06 MB/step
// of bf16 weights = 13.7 us/step. r8 cuts the stream to ~0.64 MB:
//   - r/u GRU gate weights + r/u activations in fp8 e4m3 (HW mfma fp8_fp8)
//   - n-gate + q1 head stay bf16 (h-accuracy path)
//   - w_q2 LDS-resident, w_q1w register-resident, Wz register-resident
// Plus: ds-read prefetch pipeline in B/D, hF double-buffer (no B->C barrier),
// continuous vmcnt ledger (never drains; min outstanding 5):
//   A: VMW(16)->obs | B: 10,10,6,6,6,6,6(+db0-3),4(+db4-7,nz)
//   D: VMW(5),VMW(1); issue obs',k0',k1' | E: no wait | F: VMW(13)->nz; st4
// Frag addr: bf16 shorts F[kt*512+l*8+j]; fp8 bytes F8[kt*512+l*8+j];
//   value(row=l&15, k=kt*32+((l>>4)&3)*8+j) — same mapping both dtypes.
// ---------------------------------------------------------------------------

#define B_   1024
#define L_   256
#define WD_  128
#define AD_  32
#define DD_  256
#define SD_  64
#define HD_  256
#define NA_  17
#define OUT_ 576

typedef __attribute__((ext_vector_type(8))) short bf16x8;
typedef __attribute__((ext_vector_type(4))) float f32x4;
typedef __attribute__((ext_vector_type(2))) float f32x2;
typedef __attribute__((ext_vector_type(2))) unsigned u32x2;
typedef long long fp8x8;   // 8 fp8 bytes = 2 VGPRs

#define OFF_WZ   0
#define OFF_WIH  16384
#define OFF_WHH  212992
#define OFF_WQ1H 409600
#define OFF_WQ1W 475136
#define OFF_WQ2  507904
#define OFF_WP1  540672
#define OFF_WP2  606208
#define PK_TOTAL 638976
#define OFF_ACTP_BYTES (PK_TOTAL * 2)                  // float[17*256]
#define OFF_DSCR_BYTES (OFF_ACTP_BYTES + 32768)        // 64KB dummy-store
#define OFF_W8_BYTES   (OFF_DSCR_BYTES + 65536)        // fp8 r/u weights 256KB

__device__ __forceinline__ short f2bf(float f) {
    union { float f; unsigned u; } v; v.f = f;
    unsigned r = (v.u + 0x7fffu + ((v.u >> 16) & 1u)) >> 16;  // RNE
    return (short)r;
}
__device__ __forceinline__ unsigned cvtpk(float a, float b) {
    unsigned r;
    asm("v_cvt_pk_bf16_f32 %0, %1, %2" : "=v"(r) : "v"(a), "v"(b));
    return r;
}
__device__ __forceinline__ int pk4fp8(float a, float b, float c, float d) {
    int r = __builtin_amdgcn_cvt_pk_fp8_f32(a, b, 0, false);
    r = __builtin_amdgcn_cvt_pk_fp8_f32(c, d, r, true);
    return r;
}

__device__ __forceinline__ f32x4 mfma16(bf16x8 a, bf16x8 b, f32x4 c) {
    return __builtin_amdgcn_mfma_f32_16x16x32_bf16(a, b, c, 0, 0, 0);
}
__device__ __forceinline__ f32x4 mfma8(fp8x8 a, fp8x8 b, f32x4 c) {
    return __builtin_amdgcn_mfma_f32_16x16x32_fp8_fp8(a, b, c, 0, 0, 0);
}

__device__ __forceinline__ float sigmoidf_(float x) { return 1.f / (1.f + __expf(-x)); }
__device__ __forceinline__ float tanhf_(float x)    { return 2.f / (1.f + __expf(-2.f * x)) - 1.f; }
__device__ __forceinline__ float softplusf_(float x){ return (x > 20.f) ? x : __logf(1.f + __expf(x)); }

// ---- counted asm VMEM (SGPR base + unsigned VGPR byte offset) --------------
template<int IMM>
__device__ __forceinline__ bf16x8 gload(const short* sbase, unsigned voff) {
    bf16x8 d;
    if constexpr (IMM == 0) {
        asm volatile("global_load_dwordx4 %0, %1, %2"
                     : "=v"(d) : "v"(voff), "s"(sbase));
    } else {
        asm volatile("global_load_dwordx4 %0, %1, %2 offset:%3"
                     : "=v"(d) : "v"(voff), "s"(sbase), "i"(IMM));
    }
    return d;
}
template<int IMM>
__device__ __forceinline__ fp8x8 gload8(const char* sbase, unsigned voff) {
    fp8x8 d;
    if constexpr (IMM == 0) {
        asm volatile("global_load_dwordx2 %0, %1, %2"
                     : "=v"(d) : "v"(voff), "s"(sbase));
    } else {
        asm volatile("global_load_dwordx2 %0, %1, %2 offset:%3"
                     : "=v"(d) : "v"(voff), "s"(sbase), "i"(IMM));
    }
    return d;
}
__device__ __forceinline__ f32x2 gload2f(const float* sbase, unsigned voff) {
    f32x2 d;
    asm volatile("global_load_dwordx2 %0, %1, %2 nt" : "=v"(d) : "v"(voff), "s"(sbase));
    return d;
}
__device__ __forceinline__ float gload1f(const float* sbase, unsigned voff) {
    float d;
    asm volatile("global_load_dword %0, %1, %2 nt" : "=v"(d) : "v"(voff), "s"(sbase));
    return d;
}
__device__ __forceinline__ void gstore4f(float* sbase, unsigned voff, f32x4 v) {
    asm volatile("global_store_dwordx4 %0, %1, %2 nt" :: "v"(voff), "v"(v), "s"(sbase));
}
__device__ __forceinline__ void gstore1f(float* sbase, unsigned voff, float v) {
    asm volatile("global_store_dword %0, %1, %2 nt" :: "v"(voff), "v"(v), "s"(sbase));
}

#define VMW(N) do { asm volatile("s_waitcnt vmcnt(" #N ")" ::: "memory"); \
                    __builtin_amdgcn_sched_barrier(0); } while (0)
#define BAR() do { asm volatile("s_waitcnt lgkmcnt(0)" ::: "memory"); \
                   __builtin_amdgcn_s_barrier(); \
                   __builtin_amdgcn_sched_barrier(0); } while (0)

// ---------------------------------------------------------------------------
__global__ void pack_w_kernel(const float* __restrict__ W, short* __restrict__ dst,
                              int KT, int rowOff, int srcN, int total) {
    int tid = blockIdx.x * 256 + threadIdx.x;
    if (tid >= total) return;
    int j    = tid & 7;
    int lane = (tid >> 3) & 63;
    int kt   = (tid >> 9) % KT;
    int nt   = (tid >> 9) / KT;
    int k = kt * 32 + (lane >> 4) * 8 + j;
    int n = nt * 16 + (lane & 15);
    dst[tid] = f2bf(W[(size_t)(rowOff + k) * srcN + n]);
}

// fp8 r/u gate weights: [gb 0..63][kt 0..7][512B]; gb: 0-15 ih_r, 16-31 ih_u,
// 32-47 hh_r, 48-63 hh_u (nt = gb&15)
__global__ void pack_w8_kernel(const float* __restrict__ Wih, const float* __restrict__ Whh,
                               char* __restrict__ dst) {
    int tid = blockIdx.x * 256 + threadIdx.x;   // 262144 total
    int j = tid & 7, lane = (tid >> 3) & 63, kt = (tid >> 9) & 7, gb = tid >> 12;
    int nt = gb & 15, which = gb >> 4;
    const float* W = (which < 2) ? Wih : Whh;
    int gcol = (which & 1) * 256;
    int k = kt * 32 + (lane >> 4) * 8 + j;
    int n = gcol + nt * 16 + (lane & 15);
    float v = W[(size_t)k * 768 + n];
    int p = __builtin_amdgcn_cvt_pk_fp8_f32(v, 0.f, 0, false);
    dst[tid] = (char)(p & 0xFF);
}

__global__ void act_proj_kernel(const float* __restrict__ emb, const float* __restrict__ w_in,
                                const float* __restrict__ b_in, float* __restrict__ actp) {
    int c = threadIdx.x;
    int a = blockIdx.x;
    float s = b_in[c];
    for (int i = 0; i < AD_; ++i) s += emb[a * AD_ + i] * w_in[(SD_ + i) * HD_ + c];
    actp[a * HD_ + c] = s;
}

// ---------------------------------------------------------------------------
#define RPB 16
#define NTH 1024

struct WB { fp8x8 ri, ui, rh, uh; bf16x8 ni, nh; };

template<int KT>
__device__ __forceinline__ void issueK(WB& b,
        const short* sbni, const short* sbnh,
        const char* s8ri, const char* s8ui, const char* s8rh, const char* s8uh,
        unsigned voff16, unsigned voff8) {
    constexpr int ADD   = (KT >= 4) ? 2048 : 0;   // shorts
    constexpr int IMM16 = (KT & 3) * 1024;        // bytes
    constexpr int IMM8  = KT * 512;               // bytes
    b.ri = gload8<IMM8>(s8ri, voff8);
    b.ui = gload8<IMM8>(s8ui, voff8);
    b.rh = gload8<IMM8>(s8rh, voff8);
    b.uh = gload8<IMM8>(s8uh, voff8);
    b.ni = gload<IMM16>(sbni + ADD, voff16);
    b.nh = gload<IMM16>(sbnh + ADD, voff16);
}

__launch_bounds__(NTH, 4)
__global__ void scan_kernel(const int* __restrict__ actions, const float* __restrict__ obs,
                            const float* __restrict__ noise,
                            const float* __restrict__ b_ih, const float* __restrict__ b_hh,
                            const float* __restrict__ g_ln, const float* __restrict__ beta_ln,
                            const float* __restrict__ b_q1, const float* __restrict__ b_q2,
                            const short* __restrict__ wpk, const char* __restrict__ w8,
                            const float* __restrict__ actp,
                            float* __restrict__ dscr, float* __restrict__ out) {
    __shared__ __align__(16) float ps_s [16][20];
    __shared__ __align__(16) float ps_ss[16][20];
    __shared__ __align__(16) float q2p[2][16][132];
    __shared__ __align__(16) short xF  [4096];
    __shared__ __align__(16) char  xF8 [4096];
    __shared__ __align__(16) short hFa [4096];
    __shared__ __align__(16) short hFb [4096];
    __shared__ __align__(16) char  hF8a[4096];
    __shared__ __align__(16) char  hF8b[4096];
    __shared__ __align__(16) short q1F [4096];
    __shared__ __align__(16) short zF  [1024];
    __shared__ __align__(16) short obsF[2048];
    __shared__ __align__(16) short wq2_l[32768];   // w_q2 LDS-resident (64KB)
    __shared__ __align__(16) float bq1_l[256], lng_l[256], lnb_l[256], bq2_l[128];
    __shared__ __align__(16) unsigned char act8_l[L_][16];
    __shared__ __align__(16) float actp_l[NA_][260];

    const int tid  = threadIdx.x;
    const int w    = tid >> 6;
    const int lane = tid & 63;
    const int lrow = lane & 15;
    const int lgrp = lane >> 4;
    const int row0 = blockIdx.x * RPB;
    const int c0   = w * 16 + lgrp * 4;
    const int foff = lane * 8;          // shorts
    const int b8off = lane * 8;         // bytes (fp8 frag)
    const int fwb  = (c0 >> 5) * 512 + (lrow + 16 * ((c0 >> 3) & 3)) * 8 + (c0 & 7);
    const int fwb8 = fwb;               // same formula, bytes in fp8 arrays
    const f32x4 zero4 = {0.f, 0.f, 0.f, 0.f};

    const int wu = __builtin_amdgcn_readfirstlane(w);
    const unsigned voff16 = (unsigned)lane * 16u;
    const unsigned voff8  = (unsigned)lane * 8u;
    const short* sbni  = wpk + OFF_WIH + ((32 + wu) * 8) * 512;
    const short* sbnh  = wpk + OFF_WHH + ((32 + wu) * 8) * 512;
    const char*  s8ri  = w8 + (wu * 8) * 512;
    const char*  s8ui  = w8 + ((16 + wu) * 8) * 512;
    const char*  s8rh  = w8 + ((32 + wu) * 8) * 512;
    const char*  s8uh  = w8 + ((48 + wu) * 8) * 512;
    const short* sbq1h = wpk + OFF_WQ1H + (wu * 8) * 512;
    const short* sbq1w = wpk + OFF_WQ1W + (wu * 4) * 512;
    const int khalf = wu >> 3;

    // register-resident: Wz (nt=w), Wq1w (nt=w)
    const short* wz = wpk + OFF_WZ;
    const bf16x8 Wz0 = *(const bf16x8*)&wz[(wu * 2 + 0) * 512 + foff];
    const bf16x8 Wz1 = *(const bf16x8*)&wz[(wu * 2 + 1) * 512 + foff];
    const bf16x8 Wq1w0 = *(const bf16x8*)&sbq1w[0 * 512 + foff];
    const bf16x8 Wq1w1 = *(const bf16x8*)&sbq1w[1 * 512 + foff];
    const bf16x8 Wq1w2 = *(const bf16x8*)&sbq1w[2 * 512 + foff];
    const bf16x8 Wq1w3 = *(const bf16x8*)&sbq1w[3 * 512 + foff];
    f32x4 bsr = *(const f32x4*)&b_ih[c0]       + *(const f32x4*)&b_hh[c0];
    f32x4 bsu = *(const f32x4*)&b_ih[256 + c0] + *(const f32x4*)&b_hh[256 + c0];
    f32x4 bin = *(const f32x4*)&b_ih[512 + c0];
    f32x4 bhn = *(const f32x4*)&b_hh[512 + c0];
    // PIN: compiler waitcnt for these lands HERE, not in the loop
    asm volatile("" :: "v"(bsr), "v"(bsu), "v"(bin), "v"(bhn), "v"(Wz0), "v"(Wz1),
                       "v"(Wq1w0), "v"(Wq1w1), "v"(Wq1w2), "v"(Wq1w3));

    // prologue: params/actions/actp/wq2 -> LDS; zero state
    if (tid < 256) {
        bq1_l[tid] = b_q1[tid];
        lng_l[tid] = g_ln[tid];
        lnb_l[tid] = beta_ln[tid];
    } else if (tid < 384) {
        bq2_l[tid - 256] = b_q2[tid - 256];
    }
    for (int i = tid; i < RPB * L_; i += NTH) {
        int r = i >> 8, tt = i & 255;
        act8_l[tt][r] = (unsigned char)actions[(row0 + r) * L_ + tt];
    }
    for (int i = tid; i < NA_ * HD_; i += NTH)
        actp_l[i >> 8][i & 255] = actp[i];
    for (int i = tid; i < 32768; i += NTH)
        wq2_l[i] = wpk[OFF_WQ2 + i];
    for (int i = tid; i < 4096; i += NTH) { hFa[i] = 0; hF8a[i] = 0; }
    for (int i = tid; i < 1024; i += NTH) zF[i] = 0;
    f32x4 hreg = zero4;

    unsigned obs_off = (unsigned)((row0 + w) * L_) * (WD_ * 4u) + (unsigned)lane * 8u;
    unsigned nz_off  = (unsigned)((row0 + w) * L_) * (SD_ * 4u) + (unsigned)lane * 4u;
    unsigned ho_off  = (unsigned)((row0 + lrow) * L_) * (OUT_ * 4u) + (unsigned)c0 * 4u;
    unsigned zo_off  = (unsigned)((row0 + w) * L_) * (OUT_ * 4u);
    __syncthreads();   // drains prologue VMEM; ledger starts at 0

    WB w0, w1;
    bf16x8 db0, db1, db2, db3, db4, db5, db6, db7;
    f32x2 obsv;
    float nzv;

    // PRE-ISSUE steady-state queue: [obs][k0 6][k1 6][st 4] = 17
    obsv = gload2f(obs, obs_off);
    issueK<0>(w0, sbni, sbnh, s8ri, s8ui, s8rh, s8uh, voff16, voff8);
    issueK<1>(w1, sbni, sbnh, s8ri, s8ui, s8rh, s8uh, voff16, voff8);
    {
        unsigned doff = (unsigned)tid * 16u;
        gstore4f(dscr, doff, zero4);
        gstore4f(dscr, doff + 16384u, zero4);
        gstore4f(dscr, doff + 32768u, zero4);
        gstore4f(dscr, doff + 49152u, zero4);
    }

    for (int t = 0; t < L_; ++t) {
        const short* hFc  = (t & 1) ? hFb  : hFa;   // read in B
        const char*  hF8c = (t & 1) ? hF8b : hF8a;
        short* hFn  = (t & 1) ? hFa  : hFb;         // written in C, read in D
        char*  hF8n = (t & 1) ? hF8a : hF8b;

        // ---- Phase A: xpre = z@Wz + actp[act]; LN partials; obsF stage ------
        f32x4 xp;
        {
            f32x4 a = zero4;
            a = mfma16(Wz0, *(const bf16x8*)&zF[foff], a);
            a = mfma16(Wz1, *(const bf16x8*)&zF[512 + foff], a);
            int act = act8_l[t][lrow];
            xp = a + *(const f32x4*)&actp_l[act][c0];
            float s  = xp[0] + xp[1] + xp[2] + xp[3];
            float ss = xp[0]*xp[0] + xp[1]*xp[1] + xp[2]*xp[2] + xp[3]*xp[3];
            s  += __shfl_xor(s, 16, 64);  s  += __shfl_xor(s, 32, 64);
            ss += __shfl_xor(ss, 16, 64); ss += __shfl_xor(ss, 32, 64);
            if (lgrp == 0) { ps_s[lrow][w] = s; ps_ss[lrow][w] = ss; }
        }
        VMW(16);   // obs ready
        {
            int oc = lane * 2;
            *(unsigned*)&obsF[(oc >> 5) * 512 + (w + 16 * ((oc >> 3) & 3)) * 8 + (oc & 7)]
                = cvtpk(obsv[0], obsv[1]);
        }
        BAR();   // (1)

        // ---- LN finish + xF (bf16) + xF8 (fp8) writes ------------------------
        {
            float s  = ps_s [lrow][lgrp] + ps_s [lrow][lgrp + 4]
                     + ps_s [lrow][lgrp + 8] + ps_s [lrow][lgrp + 12];
            float ss = ps_ss[lrow][lgrp] + ps_ss[lrow][lgrp + 4]
                     + ps_ss[lrow][lgrp + 8] + ps_ss[lrow][lgrp + 12];
            s  += __shfl_xor(s, 16, 64);  s  += __shfl_xor(s, 32, 64);
            ss += __shfl_xor(ss, 16, 64); ss += __shfl_xor(ss, 32, 64);
            float mean = s * (1.f / 256.f);
            float rstd = rsqrtf(ss * (1.f / 256.f) - mean * mean + 1e-5f);
            f32x4 g  = *(const f32x4*)&lng_l[c0];
            f32x4 bb = *(const f32x4*)&lnb_l[c0];
            float r0 = fmaxf((xp[0] - mean) * rstd * g[0] + bb[0], 0.f);
            float r1 = fmaxf((xp[1] - mean) * rstd * g[1] + bb[1], 0.f);
            float r2 = fmaxf((xp[2] - mean) * rstd * g[2] + bb[2], 0.f);
            float r3 = fmaxf((xp[3] - mean) * rstd * g[3] + bb[3], 0.f);
            u32x2 xb; xb[0] = cvtpk(r0, r1); xb[1] = cvtpk(r2, r3);
            *(u32x2*)&xF[fwb] = xb;
            *(int*)&xF8[fwb8] = pk4fp8(r0, r1, r2, r3);
        }
        BAR();   // (2)

        // ---- Phase B: GRU matmuls (fp8 r/u + bf16 n), ds-prefetch pipeline ---
        f32x4 ar = zero4, au = zero4, aI = zero4, aH = zero4;
        {
            bf16x8 xfE, hfE, xfO, hfO;
            fp8x8 x8E, h8E, x8O, h8O;
#define LDS_PRE(KT, xf, hf, x8, h8) \
            xf = *(const bf16x8*)&xF [(KT) * 512 + foff]; \
            hf = *(const bf16x8*)&hFc[(KT) * 512 + foff]; \
            x8 = *(const fp8x8*)&xF8 [(KT) * 512 + b8off]; \
            h8 = *(const fp8x8*)&hF8c[(KT) * 512 + b8off];
#define GRU6(W, xf, hf, x8, h8) \
            ar = mfma8(W.ri, x8, ar); ar = mfma8(W.rh, h8, ar); \
            au = mfma8(W.ui, x8, au); au = mfma8(W.uh, h8, au); \
            aI = mfma16(W.ni, xf, aI); aH = mfma16(W.nh, hf, aH);
#define ISSUE(KT, W) issueK<KT>(W, sbni, sbnh, s8ri, s8ui, s8rh, s8uh, voff16, voff8)

            LDS_PRE(0, xfE, hfE, x8E, h8E);
            LDS_PRE(1, xfO, hfO, x8O, h8O);
            VMW(10); GRU6(w0, xfE, hfE, x8E, h8E); ISSUE(2, w0);
            LDS_PRE(2, xfE, hfE, x8E, h8E);
            VMW(10); GRU6(w1, xfO, hfO, x8O, h8O); ISSUE(3, w1);
            LDS_PRE(3, xfO, hfO, x8O, h8O);
            VMW(6);  GRU6(w0, xfE, hfE, x8E, h8E); ISSUE(4, w0);
            LDS_PRE(4, xfE, hfE, x8E, h8E);
            VMW(6);  GRU6(w1, xfO, hfO, x8O, h8O); ISSUE(5, w1);
            LDS_PRE(5, xfO, hfO, x8O, h8O);
            VMW(6);  GRU6(w0, xfE, hfE, x8E, h8E); ISSUE(6, w0);
            LDS_PRE(6, xfE, hfE, x8E, h8E);
            VMW(6);  GRU6(w1, xfO, hfO, x8O, h8O); ISSUE(7, w1);
            LDS_PRE(7, xfO, hfO, x8O, h8O);
            VMW(6);  GRU6(w0, xfE, hfE, x8E, h8E);      // kt6
            db0 = gload<0>   (sbq1h, voff16);           // issue db0..3
            db1 = gload<1024>(sbq1h, voff16);
            db2 = gload<2048>(sbq1h, voff16);
            db3 = gload<3072>(sbq1h, voff16);
            VMW(4);  GRU6(w1, xfO, hfO, x8O, h8O);      // kt7
            db4 = gload<0>   (sbq1h + 2048, voff16);    // issue db4..7 + nz
            db5 = gload<1024>(sbq1h + 2048, voff16);
            db6 = gload<2048>(sbq1h + 2048, voff16);
            db7 = gload<3072>(sbq1h + 2048, voff16);
            nzv = gload1f(noise, nz_off);
            nz_off += SD_ * 4u;
#undef LDS_PRE
#undef GRU6
#undef ISSUE
        }
        // (no barrier: C writes the OTHER h buffer)

        // ---- Phase C: gates (pure VALU), write hF/hF8 [next buffer] ----------
        {
            f32x4 hv;
            #pragma unroll
            for (int j = 0; j < 4; ++j) {
                float rr = sigmoidf_(ar[j] + bsr[j]);
                float uu = sigmoidf_(au[j] + bsu[j]);
                float nn = tanhf_(aI[j] + bin[j] + rr * (aH[j] + bhn[j]));
                hv[j] = (1.f - uu) * nn + uu * hreg[j];
            }
            hreg = hv;
            u32x2 hb; hb[0] = cvtpk(hv[0], hv[1]); hb[1] = cvtpk(hv[2], hv[3]);
            *(u32x2*)&hFn[fwb] = hb;
            *(int*)&hF8n[fwb8] = pk4fp8(hv[0], hv[1], hv[2], hv[3]);
        }
        BAR();   // (4)

        // ---- Phase D: q1 = relu(h@Wq1h + obs@Wq1w + b_q1) --------------------
        {
            f32x4 aq = zero4;
            bf16x8 t0 = *(const bf16x8*)&hFn[0 * 512 + foff];
            bf16x8 t1 = *(const bf16x8*)&hFn[1 * 512 + foff];
            bf16x8 t2 = *(const bf16x8*)&hFn[2 * 512 + foff];
            bf16x8 t3 = *(const bf16x8*)&hFn[3 * 512 + foff];
            VMW(5);    // db0-3 ready
            aq = mfma16(db0, t0, aq); aq = mfma16(db1, t1, aq);
            aq = mfma16(db2, t2, aq); aq = mfma16(db3, t3, aq);
            bf16x8 t4 = *(const bf16x8*)&hFn[4 * 512 + foff];
            bf16x8 t5 = *(const bf16x8*)&hFn[5 * 512 + foff];
            bf16x8 t6 = *(const bf16x8*)&hFn[6 * 512 + foff];
            bf16x8 t7 = *(const bf16x8*)&hFn[7 * 512 + foff];
            VMW(1);    // db4-7 ready
            aq = mfma16(db4, t4, aq); aq = mfma16(db5, t5, aq);
            aq = mfma16(db6, t6, aq); aq = mfma16(db7, t7, aq);
            bf16x8 o0 = *(const bf16x8*)&obsF[0 * 512 + foff];
            bf16x8 o1 = *(const bf16x8*)&obsF[1 * 512 + foff];
            bf16x8 o2 = *(const bf16x8*)&obsF[2 * 512 + foff];
            bf16x8 o3 = *(const bf16x8*)&obsF[3 * 512 + foff];
            aq = mfma16(Wq1w0, o0, aq); aq = mfma16(Wq1w1, o1, aq);
            aq = mfma16(Wq1w2, o2, aq); aq = mfma16(Wq1w3, o3, aq);
            f32x4 bq = *(const f32x4*)&bq1_l[c0];
            u32x2 qb;
            qb[0] = cvtpk(fmaxf(aq[0] + bq[0], 0.f), fmaxf(aq[1] + bq[1], 0.f));
            qb[1] = cvtpk(fmaxf(aq[2] + bq[2], 0.f), fmaxf(aq[3] + bq[3], 0.f));
            *(u32x2*)&q1F[fwb] = qb;
        }
        // prefetch NEXT step: obs', k0', k1'
        {
            unsigned onext = obs_off + ((t < L_ - 1) ? (WD_ * 4u) : 0u);
            obsv = gload2f(obs, onext);
            obs_off = onext;
            issueK<0>(w0, sbni, sbnh, s8ri, s8ui, s8rh, s8uh, voff16, voff8);
            issueK<1>(w1, sbni, sbnh, s8ri, s8ui, s8rh, s8uh, voff16, voff8);
        }
        BAR();   // (5)

        // ---- Phase E: q2 partials from LDS-resident wq2 (no VMEM wait) -------
        {
            f32x4 a = zero4;
            #pragma unroll
            for (int i = 0; i < 4; ++i) {
                bf16x8 wf = *(const bf16x8*)&wq2_l[((wu & 7) * 8 + khalf * 4 + i) * 512 + foff];
                bf16x8 qf = *(const bf16x8*)&q1F[(khalf * 4 + i) * 512 + foff];
                a = mfma16(wf, qf, a);
            }
            *(f32x4*)&q2p[khalf][lrow][(wu & 7) * 16 + lgrp * 4] = a;
        }
        BAR();   // (6)

        // ---- Phase F: z sample; zF write; counted out-stores -----------------
        {
            int n = lane;   // wave w = row w
            VMW(13);        // nz ready ([obs' k0' k1'] = 13 behind)
            float qm = q2p[0][w][n]      + q2p[1][w][n]      + bq2_l[n];
            float ql = q2p[0][w][64 + n] + q2p[1][w][64 + n] + bq2_l[64 + n];
            float qs = softplusf_(ql) + 0.1f;
            float zv = qm + qs * nzv;
            zF[(n >> 5) * 512 + (w + 16 * ((n >> 3) & 3)) * 8 + (n & 7)] = f2bf(zv);
            unsigned zo = zo_off;
            gstore4f(out, ho_off, hreg);
            gstore1f(out, zo + (256 + n) * 4u, zv);
            gstore1f(out, zo + (448 + n) * 4u, qm);
            gstore1f(out, zo + (512 + n) * 4u, qs);
        }
        BAR();   // (7)
        ho_off += OUT_ * 4u;
        zo_off += OUT_ * 4u;
    }
    asm volatile("s_waitcnt vmcnt(0)" ::: "memory");
}

// ---------------------------------------------------------------------------
__launch_bounds__(256, 2)
__global__ void prior_kernel(const float* __restrict__ b_p1, const float* __restrict__ b_p2,
                             const short* __restrict__ wpk, float* __restrict__ out) {
    const short* wp1 = wpk + OFF_WP1;
    const short* wp2 = wpk + OFF_WP2;
    __shared__ __align__(16) short p1b[4][16][264];
    const int tid = threadIdx.x, wid = tid >> 6, lane = tid & 63;
    const int lrow = lane & 15, lgrp = lane >> 4;
    const size_t rbase = (size_t)blockIdx.x * 64 + wid * 16;
    const f32x4 zero4 = {0.f, 0.f, 0.f, 0.f};

    f32x4 acc[16];
    #pragma unroll
    for (int nt = 0; nt < 16; ++nt) acc[nt] = zero4;
    for (int kt = 0; kt < 8; ++kt) {
        const f32x4* hp = (const f32x4*)&out[(rbase + lrow) * OUT_ + kt * 32 + lgrp * 8];
        f32x4 h0 = hp[0], h1 = hp[1];
        bf16x8 a;
        a[0] = f2bf(h0[0]); a[1] = f2bf(h0[1]); a[2] = f2bf(h0[2]); a[3] = f2bf(h0[3]);
        a[4] = f2bf(h1[0]); a[5] = f2bf(h1[1]); a[6] = f2bf(h1[2]); a[7] = f2bf(h1[3]);
        #pragma unroll
        for (int nt = 0; nt < 16; ++nt) {
            bf16x8 b = *(const bf16x8*)&wp1[(nt * 8 + kt) * 512 + lane * 8];
            acc[nt] = mfma16(a, b, acc[nt]);
        }
    }
    #pragma unroll
    for (int nt = 0; nt < 16; ++nt) {
        int colb = nt * 16 + lrow;
        #pragma unroll
        for (int j = 0; j < 4; ++j)
            p1b[wid][lgrp * 4 + j][colb] = f2bf(fmaxf(acc[nt][j] + b_p1[colb], 0.f));
    }
    __syncthreads();

    f32x4 acc2[8];
    #pragma unroll
    for (int nt = 0; nt < 8; ++nt) acc2[nt] = zero4;
    for (int kt = 0; kt < 8; ++kt) {
        bf16x8 a = *(const bf16x8*)&p1b[wid][lrow][kt * 32 + lgrp * 8];
        #pragma unroll
        for (int nt = 0; nt < 8; ++nt) {
            bf16x8 b = *(const bf16x8*)&wp2[(nt * 8 + kt) * 512 + lane * 8];
            acc2[nt] = mfma16(a, b, acc2[nt]);
        }
    }
    #pragma unroll
    for (int nt = 0; nt < 8; ++nt) {
        #pragma unroll
        for (int j = 0; j < 4; ++j) {
            size_t rw = rbase + lgrp * 4 + j;
            int col = nt * 16 + lrow;
            float v = acc2[nt][j] + b_p2[col];
            if (col < 64) out[rw * OUT_ + 320 + col] = v;
            else          out[rw * OUT_ + 384 + (col - 64)] = softplusf_(v) + 0.1f;
        }
    }
}

// ---------------------------------------------------------------------------
extern "C" void kernel_launch(void* const* d_in, const int* in_sizes, int n_in,
                              void* d_out, int out_size, void* d_ws, size_t ws_size,
                              hipStream_t stream) {
    const int*   actions = (const int*)  d_in[0];
    const float* obs     = (const float*)d_in[1];
    const float* noise   = (const float*)d_in[2];
    const float* emb     = (const float*)d_in[3];
    const float* w_in    = (const float*)d_in[4];
    const float* b_in    = (const float*)d_in[5];
    const float* g_ln    = (const float*)d_in[6];
    const float* beta_ln = (const float*)d_in[7];
    const float* w_ih    = (const float*)d_in[8];
    const float* b_ih    = (const float*)d_in[9];
    const float* w_hh    = (const float*)d_in[10];
    const float* b_hh    = (const float*)d_in[11];
    const float* w_p1    = (const float*)d_in[12];
    const float* b_p1    = (const float*)d_in[13];
    const float* w_p2    = (const float*)d_in[14];
    const float* b_p2    = (const float*)d_in[15];
    const float* w_q1    = (const float*)d_in[16];
    const float* b_q1    = (const float*)d_in[17];
    const float* w_q2    = (const float*)d_in[18];
    const float* b_q2    = (const float*)d_in[19];

    short* wpk  = (short*)d_ws;
    float* actp = (float*)((char*)d_ws + OFF_ACTP_BYTES);
    float* dscr = (float*)((char*)d_ws + OFF_DSCR_BYTES);
    char*  w8   = (char*) d_ws + OFF_W8_BYTES;
    float* out  = (float*)d_out;

    auto packLaunch = [&](const float* W, int off, int KT, int rowOff, int srcN, int total) {
        pack_w_kernel<<<(total + 255) / 256, 256, 0, stream>>>(W, wpk + off, KT, rowOff, srcN, total);
    };
    packLaunch(w_in, OFF_WZ,    2, 0,   256, 64 * 256);
    packLaunch(w_ih, OFF_WIH,   8, 0,   768, 256 * 768);
    packLaunch(w_hh, OFF_WHH,   8, 0,   768, 256 * 768);
    packLaunch(w_q1, OFF_WQ1H,  8, 0,   256, 256 * 256);
    packLaunch(w_q1, OFF_WQ1W,  4, 256, 256, 128 * 256);
    packLaunch(w_q2, OFF_WQ2,   8, 0,   128, 256 * 128);
    packLaunch(w_p1, OFF_WP1,   8, 0,   256, 256 * 256);
    packLaunch(w_p2, OFF_WP2,   8, 0,   128, 256 * 128);
    pack_w8_kernel<<<1024, 256, 0, stream>>>(w_ih, w_hh, w8);
    act_proj_kernel<<<NA_, 256, 0, stream>>>(emb, w_in, b_in, actp);

    scan_kernel<<<B_ / RPB, NTH, 0, stream>>>(actions, obs, noise, b_ih, b_hh,
                                              g_ln, beta_ln, b_q1, b_q2, wpk, w8, actp, dscr, out);
    prior_kernel<<<(B_ * L_) / 64, 256, 0, stream>>>(b_p1, b_p2, wpk, out);
}

// Round 10
// 3254.137 us; speedup vs baseline: 1.1359x; 1.1359x over previous
//
#include <hip/hip_runtime.h>
#include <hip/hip_bf16.h>

// ---------------------------------------------------------------------------
// RSSM scan on MI355X — round 10: r9's 3-deep pipeline + r8's proven numerics.
// 64 blocks x 1024 thr (16 waves), RPB=16.
// fp8 ONLY for r/u gates (weights+acts) [r8: absmax 0.039]. Everything the
// output sees directly (q1/q2/obs/n-gate) stays bf16. h recursion fp32.
// Continuous vmcnt ledger (exact, never drains; min outstanding 6):
//   issues: s0-s4 -> K3..K7 | s5 -> db0-3 | s6 -> db4-7 | s7 -> eb0-3,obs',nz'
//           D -> Wz'(2),K0'-K2'(18) | F -> st4
//   waits:  A VMW(22)[Wz] | B 16,16,16,12,12,12,10,8 | D 10,6 | E 22[eb]
//           F 20[obs,nz]
//   queue:  A-entry 24 -> B-entry 22 -> D-entry 14 -> E-entry 26 -> F 22 -> 24
// Frag addr: bf16 shorts F[kt*512+l*8+j]; fp8 bytes F8[kt*512+l*8+j];
//   value(row=l&15, k=kt*32+((l>>4)&3)*8+j).
// ---------------------------------------------------------------------------

#define B_   1024
#define L_   256
#define WD_  128
#define AD_  32
#define DD_  256
#define SD_  64
#define HD_  256
#define NA_  17
#define OUT_ 576

typedef __attribute__((ext_vector_type(8))) short bf16x8;
typedef __attribute__((ext_vector_type(4))) float f32x4;
typedef __attribute__((ext_vector_type(2))) float f32x2;
typedef __attribute__((ext_vector_type(2))) unsigned u32x2;
typedef long long fp8x8;

#define OFF_WZ   0
#define OFF_WIH  16384
#define OFF_WHH  212992
#define OFF_WQ1H 409600
#define OFF_WQ1W 475136
#define OFF_WQ2  507904
#define OFF_WP1  540672
#define OFF_WP2  606208
#define PK_TOTAL 638976
#define OFF_ACTP_BYTES (PK_TOTAL * 2)
#define OFF_DSCR_BYTES (OFF_ACTP_BYTES + 32768)
#define OFF_W8_BYTES   (OFF_DSCR_BYTES + 65536)
// w8 (fp8 r/u gate weights): ih_r 0 | ih_u 64K | hh_r 128K | hh_u 192K
#define W8_IHR 0
#define W8_IHU 65536
#define W8_HHR 131072
#define W8_HHU 196608

__device__ __forceinline__ short f2bf(float f) {
    union { float f; unsigned u; } v; v.f = f;
    unsigned r = (v.u + 0x7fffu + ((v.u >> 16) & 1u)) >> 16;  // RNE
    return (short)r;
}
__device__ __forceinline__ unsigned cvtpk(float a, float b) {
    unsigned r;
    asm("v_cvt_pk_bf16_f32 %0, %1, %2" : "=v"(r) : "v"(a), "v"(b));
    return r;
}
__device__ __forceinline__ int pk4fp8(float a, float b, float c, float d) {
    int r = __builtin_amdgcn_cvt_pk_fp8_f32(a, b, 0, false);
    r = __builtin_amdgcn_cvt_pk_fp8_f32(c, d, r, true);
    return r;
}

__device__ __forceinline__ f32x4 mfma16(bf16x8 a, bf16x8 b, f32x4 c) {
    return __builtin_amdgcn_mfma_f32_16x16x32_bf16(a, b, c, 0, 0, 0);
}
__device__ __forceinline__ f32x4 mfma8(fp8x8 a, fp8x8 b, f32x4 c) {
    return __builtin_amdgcn_mfma_f32_16x16x32_fp8_fp8(a, b, c, 0, 0, 0);
}

__device__ __forceinline__ float sigmoidf_(float x) { return 1.f / (1.f + __expf(-x)); }
__device__ __forceinline__ float tanhf_(float x)    { return 2.f / (1.f + __expf(-2.f * x)) - 1.f; }
__device__ __forceinline__ float softplusf_(float x){ return (x > 20.f) ? x : __logf(1.f + __expf(x)); }

template<int IMM>
__device__ __forceinline__ bf16x8 gload(const short* sbase, unsigned voff) {
    bf16x8 d;
    if constexpr (IMM == 0) {
        asm volatile("global_load_dwordx4 %0, %1, %2" : "=v"(d) : "v"(voff), "s"(sbase));
    } else {
        asm volatile("global_load_dwordx4 %0, %1, %2 offset:%3"
                     : "=v"(d) : "v"(voff), "s"(sbase), "i"(IMM));
    }
    return d;
}
template<int IMM>
__device__ __forceinline__ fp8x8 gload8(const char* sbase, unsigned voff) {
    fp8x8 d;
    if constexpr (IMM == 0) {
        asm volatile("global_load_dwordx2 %0, %1, %2" : "=v"(d) : "v"(voff), "s"(sbase));
    } else {
        asm volatile("global_load_dwordx2 %0, %1, %2 offset:%3"
                     : "=v"(d) : "v"(voff), "s"(sbase), "i"(IMM));
    }
    return d;
}
__device__ __forceinline__ f32x2 gload2f(const float* sbase, unsigned voff) {
    f32x2 d;
    asm volatile("global_load_dwordx2 %0, %1, %2 nt" : "=v"(d) : "v"(voff), "s"(sbase));
    return d;
}
__device__ __forceinline__ float gload1f(const float* sbase, unsigned voff) {
    float d;
    asm volatile("global_load_dword %0, %1, %2 nt" : "=v"(d) : "v"(voff), "s"(sbase));
    return d;
}
__device__ __forceinline__ void gstore4f(float* sbase, unsigned voff, f32x4 v) {
    asm volatile("global_store_dwordx4 %0, %1, %2 nt" :: "v"(voff), "v"(v), "s"(sbase));
}
__device__ __forceinline__ void gstore1f(float* sbase, unsigned voff, float v) {
    asm volatile("global_store_dword %0, %1, %2 nt" :: "v"(voff), "v"(v), "s"(sbase));
}

#define VMW(N) do { asm volatile("s_waitcnt vmcnt(" #N ")" ::: "memory"); \
                    __builtin_amdgcn_sched_barrier(0); } while (0)
#define BAR() do { asm volatile("s_waitcnt lgkmcnt(0)" ::: "memory"); \
                   __builtin_amdgcn_s_barrier(); \
                   __builtin_amdgcn_sched_barrier(0); } while (0)

// ---------------------------------------------------------------------------
__global__ void pack_w_kernel(const float* __restrict__ W, short* __restrict__ dst,
                              int KT, int rowOff, int srcN, int total) {
    int tid = blockIdx.x * 256 + threadIdx.x;
    if (tid >= total) return;
    int j    = tid & 7;
    int lane = (tid >> 3) & 63;
    int kt   = (tid >> 9) % KT;
    int nt   = (tid >> 9) / KT;
    int k = kt * 32 + (lane >> 4) * 8 + j;
    int n = nt * 16 + (lane & 15);
    dst[tid] = f2bf(W[(size_t)(rowOff + k) * srcN + n]);
}

__global__ void pack_f8_kernel(const float* __restrict__ W, char* __restrict__ dst,
                               int KT, int rowOff, int colOff, int srcN, int total) {
    int tid = blockIdx.x * 256 + threadIdx.x;
    if (tid >= total) return;
    int j    = tid & 7;
    int lane = (tid >> 3) & 63;
    int kt   = (tid >> 9) % KT;
    int nt   = (tid >> 9) / KT;
    int k = kt * 32 + (lane >> 4) * 8 + j;
    int n = colOff + nt * 16 + (lane & 15);
    float v = W[(size_t)(rowOff + k) * srcN + n];
    int p = __builtin_amdgcn_cvt_pk_fp8_f32(v, 0.f, 0, false);
    dst[tid] = (char)(p & 0xFF);
}

__global__ void act_proj_kernel(const float* __restrict__ emb, const float* __restrict__ w_in,
                                const float* __restrict__ b_in, float* __restrict__ actp) {
    int c = threadIdx.x;
    int a = blockIdx.x;
    float s = b_in[c];
    for (int i = 0; i < AD_; ++i) s += emb[a * AD_ + i] * w_in[(SD_ + i) * HD_ + c];
    actp[a * HD_ + c] = s;
}

// ---------------------------------------------------------------------------
#define RPB 16
#define NTH 1024

struct WB { fp8x8 ri, ui, rh, uh; bf16x8 ni, nh; };   // 16 VGPR

template<int KT>
__device__ __forceinline__ void issueK(WB& b,
        const short* sbni, const short* sbnh,
        const char* s8ri, const char* s8ui, const char* s8rh, const char* s8uh,
        unsigned voff16, unsigned voff8) {
    constexpr int ADD   = (KT >= 4) ? 2048 : 0;
    constexpr int IMM16 = (KT & 3) * 1024;
    constexpr int IMM8  = KT * 512;
    b.ri = gload8<IMM8>(s8ri, voff8);
    b.ui = gload8<IMM8>(s8ui, voff8);
    b.rh = gload8<IMM8>(s8rh, voff8);
    b.uh = gload8<IMM8>(s8uh, voff8);
    b.ni = gload<IMM16>(sbni + ADD, voff16);
    b.nh = gload<IMM16>(sbnh + ADD, voff16);
}

__launch_bounds__(NTH, 4)
__global__ void scan_kernel(const int* __restrict__ actions, const float* __restrict__ obs,
                            const float* __restrict__ noise,
                            const float* __restrict__ b_ih, const float* __restrict__ b_hh,
                            const float* __restrict__ g_ln, const float* __restrict__ beta_ln,
                            const float* __restrict__ b_q1, const float* __restrict__ b_q2,
                            const short* __restrict__ wpk, const char* __restrict__ w8,
                            const float* __restrict__ actp,
                            float* __restrict__ dscr, float* __restrict__ out) {
    __shared__ __align__(16) float ps_s [16][20];
    __shared__ __align__(16) float ps_ss[16][20];
    __shared__ __align__(16) float q2p[2][16][132];
    __shared__ __align__(16) short xF  [4096];
    __shared__ __align__(16) char  xF8 [4096];
    __shared__ __align__(16) short hFa [4096];
    __shared__ __align__(16) short hFb [4096];
    __shared__ __align__(16) char  h8a [4096];
    __shared__ __align__(16) char  h8b [4096];
    __shared__ __align__(16) short q1F [4096];
    __shared__ __align__(16) short zF  [1024];
    __shared__ __align__(16) short obsF[2048];
    __shared__ __align__(16) float bsr_l[256], bsu_l[256], bin_l[256], bhn_l[256];
    __shared__ __align__(16) float bq1_l[256], lng_l[256], lnb_l[256], bq2_l[128];
    __shared__ __align__(16) unsigned char act8_l[L_][16];
    __shared__ __align__(16) float actp_l[NA_][260];

    const int tid  = threadIdx.x;
    const int w    = tid >> 6;
    const int lane = tid & 63;
    const int lrow = lane & 15;
    const int lgrp = lane >> 4;
    const int row0 = blockIdx.x * RPB;
    const int c0   = w * 16 + lgrp * 4;
    const int foff = lane * 8;          // shorts
    const int b8off = lane * 8;         // bytes
    const int fwb  = (c0 >> 5) * 512 + (lrow + 16 * ((c0 >> 3) & 3)) * 8 + (c0 & 7);
    const f32x4 zero4 = {0.f, 0.f, 0.f, 0.f};

    const int wu = __builtin_amdgcn_readfirstlane(w);
    const unsigned voff16 = (unsigned)lane * 16u;
    const unsigned voff8  = (unsigned)lane * 8u;
    const short* sbwz = wpk + OFF_WZ + (wu * 2) * 512;
    const short* sbni = wpk + OFF_WIH + ((32 + wu) * 8) * 512;
    const short* sbnh = wpk + OFF_WHH + ((32 + wu) * 8) * 512;
    const char* s8ri  = w8 + W8_IHR + (wu * 8) * 512;
    const char* s8ui  = w8 + W8_IHU + (wu * 8) * 512;
    const char* s8rh  = w8 + W8_HHR + (wu * 8) * 512;
    const char* s8uh  = w8 + W8_HHU + (wu * 8) * 512;
    const short* sbq1h = wpk + OFF_WQ1H + (wu * 8) * 512;
    const short* sbq1w = wpk + OFF_WQ1W + (wu * 4) * 512;
    const int khalf = wu >> 3;
    const short* sbq2 = wpk + OFF_WQ2 + ((wu & 7) * 8 + khalf * 4) * 512;

    // Wq1w register-resident (bf16, nt=w)
    const bf16x8 Wq1w0 = *(const bf16x8*)&sbq1w[0 * 512 + foff];
    const bf16x8 Wq1w1 = *(const bf16x8*)&sbq1w[1 * 512 + foff];
    const bf16x8 Wq1w2 = *(const bf16x8*)&sbq1w[2 * 512 + foff];
    const bf16x8 Wq1w3 = *(const bf16x8*)&sbq1w[3 * 512 + foff];
    asm volatile("" :: "v"(Wq1w0), "v"(Wq1w1), "v"(Wq1w2), "v"(Wq1w3));  // pin

    // prologue: params/actions/actp -> LDS; zero state
    if (tid < 256) {
        bsr_l[tid] = b_ih[tid] + b_hh[tid];
        bsu_l[tid] = b_ih[256 + tid] + b_hh[256 + tid];
        bin_l[tid] = b_ih[512 + tid];
        bhn_l[tid] = b_hh[512 + tid];
        bq1_l[tid] = b_q1[tid];
        lng_l[tid] = g_ln[tid];
        lnb_l[tid] = beta_ln[tid];
    } else if (tid < 384) {
        bq2_l[tid - 256] = b_q2[tid - 256];
    }
    for (int i = tid; i < RPB * L_; i += NTH) {
        int r = i >> 8, tt = i & 255;
        act8_l[tt][r] = (unsigned char)actions[(row0 + r) * L_ + tt];
    }
    for (int i = tid; i < NA_ * HD_; i += NTH)
        actp_l[i >> 8][i & 255] = actp[i];
    for (int i = tid; i < 4096; i += NTH) { hFa[i] = 0; h8a[i] = 0; }
    for (int i = tid; i < 1024; i += NTH) zF[i] = 0;
    f32x4 hreg = zero4;

    unsigned obs_off = (unsigned)((row0 + w) * L_) * (WD_ * 4u) + (unsigned)lane * 8u;
    unsigned nz_off  = (unsigned)((row0 + w) * L_) * (SD_ * 4u) + (unsigned)lane * 4u;
    unsigned ho_off  = (unsigned)((row0 + lrow) * L_) * (OUT_ * 4u) + (unsigned)c0 * 4u;
    unsigned zo_off  = (unsigned)((row0 + w) * L_) * (OUT_ * 4u);
    __syncthreads();   // drains prologue VMEM; ledger starts at 0

    WB w0, w1, w2;
    bf16x8 db0, db1, db2, db3, db4, db5, db6, db7, eb0, eb1, eb2, eb3;
    bf16x8 wzb0, wzb1;
    f32x2 obsv, obsv_n;
    float nzv, nzv_n;

    // BOOTSTRAP: [obs nz Wz(2) K0 K1 K2]=22; VMW(20) -> obs,nz done; st4 -> 24
    obsv = gload2f(obs, obs_off);
    nzv  = gload1f(noise, nz_off);
    wzb0 = gload<0>   (sbwz, voff16);
    wzb1 = gload<1024>(sbwz, voff16);
    issueK<0>(w0, sbni, sbnh, s8ri, s8ui, s8rh, s8uh, voff16, voff8);
    issueK<1>(w1, sbni, sbnh, s8ri, s8ui, s8rh, s8uh, voff16, voff8);
    issueK<2>(w2, sbni, sbnh, s8ri, s8ui, s8rh, s8uh, voff16, voff8);
    VMW(20);
    {
        unsigned doff = (unsigned)tid * 16u;
        gstore4f(dscr, doff, zero4);
        gstore4f(dscr, doff + 16384u, zero4);
        gstore4f(dscr, doff + 32768u, zero4);
        gstore4f(dscr, doff + 49152u, zero4);
    }

    for (int t = 0; t < L_; ++t) {
        const short* hFc = (t & 1) ? hFb : hFa;
        const char*  h8c = (t & 1) ? h8b : h8a;
        short* hFn = (t & 1) ? hFa : hFb;
        char*  h8n = (t & 1) ? h8a : h8b;

        // ---- Phase A: xpre = z@Wz + actp[act]; LN partials; obsF stage ------
        f32x4 xp;
        {
            VMW(22);   // Wz pair complete ([K0-2 st4]=22 behind)
            f32x4 a = zero4;
            a = mfma16(wzb0, *(const bf16x8*)&zF[foff], a);
            a = mfma16(wzb1, *(const bf16x8*)&zF[512 + foff], a);
            int act = act8_l[t][lrow];
            xp = a + *(const f32x4*)&actp_l[act][c0];
            float s  = xp[0] + xp[1] + xp[2] + xp[3];
            float ss = xp[0]*xp[0] + xp[1]*xp[1] + xp[2]*xp[2] + xp[3]*xp[3];
            s  += __shfl_xor(s, 16, 64);  s  += __shfl_xor(s, 32, 64);
            ss += __shfl_xor(ss, 16, 64); ss += __shfl_xor(ss, 32, 64);
            if (lgrp == 0) { ps_s[lrow][w] = s; ps_ss[lrow][w] = ss; }
            // obs -> obsF bf16 (wave w = row w; 2 shorts per lane)
            int oc = lane * 2;
            *(unsigned*)&obsF[(oc >> 5) * 512 + (w + 16 * ((oc >> 3) & 3)) * 8 + (oc & 7)]
                = cvtpk(obsv[0], obsv[1]);
        }
        BAR();   // (1)

        // ---- LN finish + xF (bf16) + xF8 (fp8) -------------------------------
        {
            float s  = ps_s [lrow][lgrp] + ps_s [lrow][lgrp + 4]
                     + ps_s [lrow][lgrp + 8] + ps_s [lrow][lgrp + 12];
            float ss = ps_ss[lrow][lgrp] + ps_ss[lrow][lgrp + 4]
                     + ps_ss[lrow][lgrp + 8] + ps_ss[lrow][lgrp + 12];
            s  += __shfl_xor(s, 16, 64);  s  += __shfl_xor(s, 32, 64);
            ss += __shfl_xor(ss, 16, 64); ss += __shfl_xor(ss, 32, 64);
            float mean = s * (1.f / 256.f);
            float rstd = rsqrtf(ss * (1.f / 256.f) - mean * mean + 1e-5f);
            f32x4 g  = *(const f32x4*)&lng_l[c0];
            f32x4 bb = *(const f32x4*)&lnb_l[c0];
            float r0 = fmaxf((xp[0] - mean) * rstd * g[0] + bb[0], 0.f);
            float r1 = fmaxf((xp[1] - mean) * rstd * g[1] + bb[1], 0.f);
            float r2 = fmaxf((xp[2] - mean) * rstd * g[2] + bb[2], 0.f);
            float r3 = fmaxf((xp[3] - mean) * rstd * g[3] + bb[3], 0.f);
            u32x2 xb; xb[0] = cvtpk(r0, r1); xb[1] = cvtpk(r2, r3);
            *(u32x2*)&xF[fwb] = xb;
            *(int*)&xF8[fwb] = pk4fp8(r0, r1, r2, r3);
        }
        BAR();   // (2)

        // ---- Phase B: GRU, 3-slot-deep pipeline ------------------------------
        f32x4 ar = zero4, au = zero4, aI = zero4, aH = zero4;
#define SLOT(KT, WBUF) { \
        fp8x8 x8 = *(const fp8x8*)&xF8[(KT) * 512 + b8off]; \
        fp8x8 h8 = *(const fp8x8*)&h8c[(KT) * 512 + b8off]; \
        bf16x8 xf = *(const bf16x8*)&xF [(KT) * 512 + foff]; \
        bf16x8 hf = *(const bf16x8*)&hFc[(KT) * 512 + foff]; \
        ar = mfma8(WBUF.ri, x8, ar); ar = mfma8(WBUF.rh, h8, ar); \
        au = mfma8(WBUF.ui, x8, au); au = mfma8(WBUF.uh, h8, au); \
        aI = mfma16(WBUF.ni, xf, aI); aH = mfma16(WBUF.nh, hf, aH); }
#define ISSUE(KT, W) issueK<KT>(W, sbni, sbnh, s8ri, s8ui, s8rh, s8uh, voff16, voff8)

        VMW(16); SLOT(0, w0) ISSUE(3, w0);
        VMW(16); SLOT(1, w1) ISSUE(4, w1);
        VMW(16); SLOT(2, w2) ISSUE(5, w2);
        VMW(12); SLOT(3, w0) ISSUE(6, w0);
        VMW(12); SLOT(4, w1) ISSUE(7, w1);
        VMW(12); SLOT(5, w2)
        db0 = gload<0>   (sbq1h, voff16);
        db1 = gload<1024>(sbq1h, voff16);
        db2 = gload<2048>(sbq1h, voff16);
        db3 = gload<3072>(sbq1h, voff16);
        VMW(10); SLOT(6, w0)
        db4 = gload<0>   (sbq1h + 2048, voff16);
        db5 = gload<1024>(sbq1h + 2048, voff16);
        db6 = gload<2048>(sbq1h + 2048, voff16);
        db7 = gload<3072>(sbq1h + 2048, voff16);
        VMW(8);  SLOT(7, w1)
        eb0 = gload<0>   (sbq2, voff16);
        eb1 = gload<1024>(sbq2, voff16);
        eb2 = gload<2048>(sbq2, voff16);
        eb3 = gload<3072>(sbq2, voff16);
        {
            unsigned onext = obs_off + ((t < L_ - 1) ? (WD_ * 4u) : 0u);
            unsigned nnext = nz_off  + ((t < L_ - 1) ? (SD_ * 4u) : 0u);
            obsv_n = gload2f(obs, onext);
            nzv_n  = gload1f(noise, nnext);
            obs_off = onext; nz_off = nnext;
        }
#undef SLOT
#undef ISSUE
        // (no barrier: C writes the other h buffers)

        // ---- Phase C: gates (VALU), write hFn/h8n ----------------------------
        {
            f32x4 bsr = *(const f32x4*)&bsr_l[c0];
            f32x4 bsu = *(const f32x4*)&bsu_l[c0];
            f32x4 bin = *(const f32x4*)&bin_l[c0];
            f32x4 bhn = *(const f32x4*)&bhn_l[c0];
            f32x4 hv;
            #pragma unroll
            for (int j = 0; j < 4; ++j) {
                float rr = sigmoidf_(ar[j] + bsr[j]);
                float uu = sigmoidf_(au[j] + bsu[j]);
                float nn = tanhf_(aI[j] + bin[j] + rr * (aH[j] + bhn[j]));
                hv[j] = (1.f - uu) * nn + uu * hreg[j];
            }
            hreg = hv;
            u32x2 hb; hb[0] = cvtpk(hv[0], hv[1]); hb[1] = cvtpk(hv[2], hv[3]);
            *(u32x2*)&hFn[fwb] = hb;
            *(int*)&h8n[fwb] = pk4fp8(hv[0], hv[1], hv[2], hv[3]);
        }
        BAR();   // (4)

        // ---- Phase D: q1 = relu(h@Wq1h + obs@Wq1w + b_q1) [bf16] -------------
        {
            f32x4 aq = zero4;
            bf16x8 t0 = *(const bf16x8*)&hFn[0 * 512 + foff];
            bf16x8 t1 = *(const bf16x8*)&hFn[1 * 512 + foff];
            bf16x8 t2 = *(const bf16x8*)&hFn[2 * 512 + foff];
            bf16x8 t3 = *(const bf16x8*)&hFn[3 * 512 + foff];
            VMW(10);   // db0-3 ready
            aq = mfma16(db0, t0, aq); aq = mfma16(db1, t1, aq);
            aq = mfma16(db2, t2, aq); aq = mfma16(db3, t3, aq);
            bf16x8 t4 = *(const bf16x8*)&hFn[4 * 512 + foff];
            bf16x8 t5 = *(const bf16x8*)&hFn[5 * 512 + foff];
            bf16x8 t6 = *(const bf16x8*)&hFn[6 * 512 + foff];
            bf16x8 t7 = *(const bf16x8*)&hFn[7 * 512 + foff];
            VMW(6);    // db4-7 ready
            aq = mfma16(db4, t4, aq); aq = mfma16(db5, t5, aq);
            aq = mfma16(db6, t6, aq); aq = mfma16(db7, t7, aq);
            // issue NEXT step stream: Wz'(2), K0-2'(18)
            wzb0 = gload<0>   (sbwz, voff16);
            wzb1 = gload<1024>(sbwz, voff16);
            issueK<0>(w0, sbni, sbnh, s8ri, s8ui, s8rh, s8uh, voff16, voff8);
            issueK<1>(w1, sbni, sbnh, s8ri, s8ui, s8rh, s8uh, voff16, voff8);
            issueK<2>(w2, sbni, sbnh, s8ri, s8ui, s8rh, s8uh, voff16, voff8);
            // obs part (register weights, LDS obsF)
            bf16x8 o0 = *(const bf16x8*)&obsF[0 * 512 + foff];
            bf16x8 o1 = *(const bf16x8*)&obsF[1 * 512 + foff];
            bf16x8 o2 = *(const bf16x8*)&obsF[2 * 512 + foff];
            bf16x8 o3 = *(const bf16x8*)&obsF[3 * 512 + foff];
            aq = mfma16(Wq1w0, o0, aq); aq = mfma16(Wq1w1, o1, aq);
            aq = mfma16(Wq1w2, o2, aq); aq = mfma16(Wq1w3, o3, aq);
            f32x4 bq = *(const f32x4*)&bq1_l[c0];
            u32x2 qb;
            qb[0] = cvtpk(fmaxf(aq[0] + bq[0], 0.f), fmaxf(aq[1] + bq[1], 0.f));
            qb[1] = cvtpk(fmaxf(aq[2] + bq[2], 0.f), fmaxf(aq[3] + bq[3], 0.f));
            *(u32x2*)&q1F[fwb] = qb;
        }
        BAR();   // (5)

        // ---- Phase E: q2 partials (streamed eb, C+D lead) --------------------
        {
            f32x4 a = zero4;
            VMW(22);   // eb done; [obs' nz' Wz' K0-2'] = 22 behind
            bf16x8 q0 = *(const bf16x8*)&q1F[(khalf * 4 + 0) * 512 + foff];
            bf16x8 q1 = *(const bf16x8*)&q1F[(khalf * 4 + 1) * 512 + foff];
            bf16x8 q2 = *(const bf16x8*)&q1F[(khalf * 4 + 2) * 512 + foff];
            bf16x8 q3 = *(const bf16x8*)&q1F[(khalf * 4 + 3) * 512 + foff];
            a = mfma16(eb0, q0, a); a = mfma16(eb1, q1, a);
            a = mfma16(eb2, q2, a); a = mfma16(eb3, q3, a);
            *(f32x4*)&q2p[khalf][lrow][(wu & 7) * 16 + lgrp * 4] = a;
        }
        BAR();   // (6)

        // ---- Phase F: z sample; zF; counted out-stores -----------------------
        {
            int n = lane;   // wave w = row w
            VMW(20);        // obs',nz' done; [Wz' K0-2'] = 20 behind
            float qm = q2p[0][w][n]      + q2p[1][w][n]      + bq2_l[n];
            float ql = q2p[0][w][64 + n] + q2p[1][w][64 + n] + bq2_l[64 + n];
            float qs = softplusf_(ql) + 0.1f;
            float zv = qm + qs * nzv;
            zF[(n >> 5) * 512 + (w + 16 * ((n >> 3) & 3)) * 8 + (n & 7)] = f2bf(zv);
            unsigned zo = zo_off;
            gstore4f(out, ho_off, hreg);
            gstore1f(out, zo + (256 + n) * 4u, zv);
            gstore1f(out, zo + (448 + n) * 4u, qm);
            gstore1f(out, zo + (512 + n) * 4u, qs);
            obsv = obsv_n;
            nzv  = nzv_n;
        }
        BAR();   // (7)
        ho_off += OUT_ * 4u;
        zo_off += OUT_ * 4u;
    }
    asm volatile("s_waitcnt vmcnt(0)" ::: "memory");
}

// ---------------------------------------------------------------------------
__launch_bounds__(256, 2)
__global__ void prior_kernel(const float* __restrict__ b_p1, const float* __restrict__ b_p2,
                             const short* __restrict__ wpk, float* __restrict__ out) {
    const short* wp1 = wpk + OFF_WP1;
    const short* wp2 = wpk + OFF_WP2;
    __shared__ __align__(16) short p1b[4][16][264];
    const int tid = threadIdx.x, wid = tid >> 6, lane = tid & 63;
    const int lrow = lane & 15, lgrp = lane >> 4;
    const size_t rbase = (size_t)blockIdx.x * 64 + wid * 16;
    const f32x4 zero4 = {0.f, 0.f, 0.f, 0.f};

    f32x4 acc[16];
    #pragma unroll
    for (int nt = 0; nt < 16; ++nt) acc[nt] = zero4;
    for (int kt = 0; kt < 8; ++kt) {
        const f32x4* hp = (const f32x4*)&out[(rbase + lrow) * OUT_ + kt * 32 + lgrp * 8];
        f32x4 h0 = hp[0], h1 = hp[1];
        bf16x8 a;
        a[0] = f2bf(h0[0]); a[1] = f2bf(h0[1]); a[2] = f2bf(h0[2]); a[3] = f2bf(h0[3]);
        a[4] = f2bf(h1[0]); a[5] = f2bf(h1[1]); a[6] = f2bf(h1[2]); a[7] = f2bf(h1[3]);
        #pragma unroll
        for (int nt = 0; nt < 16; ++nt) {
            bf16x8 b = *(const bf16x8*)&wp1[(nt * 8 + kt) * 512 + lane * 8];
            acc[nt] = mfma16(a, b, acc[nt]);
        }
    }
    #pragma unroll
    for (int nt = 0; nt < 16; ++nt) {
        int colb = nt * 16 + lrow;
        #pragma unroll
        for (int j = 0; j < 4; ++j)
            p1b[wid][lgrp * 4 + j][colb] = f2bf(fmaxf(acc[nt][j] + b_p1[colb], 0.f));
    }
    __syncthreads();

    f32x4 acc2[8];
    #pragma unroll
    for (int nt = 0; nt < 8; ++nt) acc2[nt] = zero4;
    for (int kt = 0; kt < 8; ++kt) {
        bf16x8 a = *(const bf16x8*)&p1b[wid][lrow][kt * 32 + lgrp * 8];
        #pragma unroll
        for (int nt = 0; nt < 8; ++nt) {
            bf16x8 b = *(const bf16x8*)&wp2[(nt * 8 + kt) * 512 + lane * 8];
            acc2[nt] = mfma16(a, b, acc2[nt]);
        }
    }
    #pragma unroll
    for (int nt = 0; nt < 8; ++nt) {
        #pragma unroll
        for (int j = 0; j < 4; ++j) {
            size_t rw = rbase + lgrp * 4 + j;
            int col = nt * 16 + lrow;
            float v = acc2[nt][j] + b_p2[col];
            if (col < 64) out[rw * OUT_ + 320 + col] = v;
            else          out[rw * OUT_ + 384 + (col - 64)] = softplusf_(v) + 0.1f;
        }
    }
}

// ---------------------------------------------------------------------------
extern "C" void kernel_launch(void* const* d_in, const int* in_sizes, int n_in,
                              void* d_out, int out_size, void* d_ws, size_t ws_size,
                              hipStream_t stream) {
    const int*   actions = (const int*)  d_in[0];
    const float* obs     = (const float*)d_in[1];
    const float* noise   = (const float*)d_in[2];
    const float* emb     = (const float*)d_in[3];
    const float* w_in    = (const float*)d_in[4];
    const float* b_in    = (const float*)d_in[5];
    const float* g_ln    = (const float*)d_in[6];
    const float* beta_ln = (const float*)d_in[7];
    const float* w_ih    = (const float*)d_in[8];
    const float* b_ih    = (const float*)d_in[9];
    const float* w_hh    = (const float*)d_in[10];
    const float* b_hh    = (const float*)d_in[11];
    const float* w_p1    = (const float*)d_in[12];
    const float* b_p1    = (const float*)d_in[13];
    const float* w_p2    = (const float*)d_in[14];
    const float* b_p2    = (const float*)d_in[15];
    const float* w_q1    = (const float*)d_in[16];
    const float* b_q1    = (const float*)d_in[17];
    const float* w_q2    = (const float*)d_in[18];
    const float* b_q2    = (const float*)d_in[19];

    short* wpk  = (short*)d_ws;
    float* actp = (float*)((char*)d_ws + OFF_ACTP_BYTES);
    float* dscr = (float*)((char*)d_ws + OFF_DSCR_BYTES);
    char*  w8   = (char*) d_ws + OFF_W8_BYTES;
    float* out  = (float*)d_out;

    auto packLaunch = [&](const float* W, int off, int KT, int rowOff, int srcN, int total) {
        pack_w_kernel<<<(total + 255) / 256, 256, 0, stream>>>(W, wpk + off, KT, rowOff, srcN, total);
    };
    packLaunch(w_in, OFF_WZ,    2, 0,   256, 64 * 256);
    packLaunch(w_ih, OFF_WIH,   8, 0,   768, 256 * 768);
    packLaunch(w_hh, OFF_WHH,   8, 0,   768, 256 * 768);
    packLaunch(w_q1, OFF_WQ1H,  8, 0,   256, 256 * 256);
    packLaunch(w_q1, OFF_WQ1W,  4, 256, 256, 128 * 256);
    packLaunch(w_q2, OFF_WQ2,   8, 0,   128, 256 * 128);
    packLaunch(w_p1, OFF_WP1,   8, 0,   256, 256 * 256);
    packLaunch(w_p2, OFF_WP2,   8, 0,   128, 256 * 128);

    auto pack8 = [&](const float* W, int dstOff, int colOff) {
        pack_f8_kernel<<<256, 256, 0, stream>>>(W, w8 + dstOff, 8, 0, colOff, 768, 65536);
    };
    pack8(w_ih, W8_IHR, 0);
    pack8(w_ih, W8_IHU, 256);
    pack8(w_hh, W8_HHR, 0);
    pack8(w_hh, W8_HHU, 256);
    act_proj_kernel<<<NA_, 256, 0, stream>>>(emb, w_in, b_in, actp);

    scan_kernel<<<B_ / RPB, NTH, 0, stream>>>(actions, obs, noise, b_ih, b_hh,
                                              g_ln, beta_ln, b_q1, b_q2, wpk, w8, actp, dscr, out);
    prior_kernel<<<(B_ * L_) / 64, 256, 0, stream>>>(b_p1, b_p2, wpk, out);
}

// Round 11
// 2786.874 us; speedup vs baseline: 1.3263x; 1.1677x over previous
//
#include <hip/hip_runtime.h>
#include <hip/hip_bf16.h>

// ---------------------------------------------------------------------------
// RSSM scan on MI355X — round 11: shrink stream again (now throughput-bound).
// 64 blocks x 1024 thr (16 waves), RPB=16. r10's 3-deep pipeline + ledger
// kept verbatim (same load counts everywhere). Changes:
//   - ALL GRU gates (r/u/n) fp8: weights + x/h activations -> B stream 24KB/wave
//   - q1h (db) fp8 (h-side only) -> 4KB/wave
//   - bf16 xF/hF arrays deleted (B and D consume fp8 x/h only)
//   - obs / q1 acts / q2 / Wz stay bf16 (r9 lesson: output-path fp8 fails)
// Stream: ~35KB/wave/step = ~560KB/CU/step (was 736KB).
// Ledger (identical to r10, re-audited):
//   A VMW(22)[Wz] | B 16,16,16,12,12,12,10,8 (K3..K7, db0-3, db4-7, eb+obs+nz)
//   D 10,6 then issue Wz'+K0-2' | E 22[eb] | F 20[obs,nz] + st4
// Frag addr: bf16 shorts F[kt*512+l*8+j]; fp8 bytes F8[kt*512+l*8+j];
//   value(row=l&15, k=kt*32+((l>>4)&3)*8+j).
// ---------------------------------------------------------------------------

#define B_   1024
#define L_   256
#define WD_  128
#define AD_  32
#define DD_  256
#define SD_  64
#define HD_  256
#define NA_  17
#define OUT_ 576

typedef __attribute__((ext_vector_type(8))) short bf16x8;
typedef __attribute__((ext_vector_type(4))) float f32x4;
typedef __attribute__((ext_vector_type(2))) float f32x2;
typedef __attribute__((ext_vector_type(2))) unsigned u32x2;
typedef long long fp8x8;

// bf16 packed weights (shorts): only what bf16 paths still need
#define OFF_WZ   0         // 64 x 256
#define OFF_WQ1W 16384     // 128 x 256 (register-resident q1 obs-side)
#define OFF_WQ2  49152     // 256 x 128
#define OFF_WP1  81920     // 256 x 256
#define OFF_WP2  147456    // 256 x 128
#define PK_TOTAL 180224
#define OFF_ACTP_BYTES (PK_TOTAL * 2)
#define OFF_DSCR_BYTES (OFF_ACTP_BYTES + 32768)
#define OFF_W8_BYTES   (OFF_DSCR_BYTES + 65536)
// w8 (fp8): ih_r | ih_u | ih_n | hh_r | hh_u | hh_n | q1h  (7 x 64KB)
#define W8_IHR 0
#define W8_IHU 65536
#define W8_IHN 131072
#define W8_HHR 196608
#define W8_HHU 262144
#define W8_HHN 327680
#define W8_Q1H 393216

__device__ __forceinline__ short f2bf(float f) {
    union { float f; unsigned u; } v; v.f = f;
    unsigned r = (v.u + 0x7fffu + ((v.u >> 16) & 1u)) >> 16;  // RNE
    return (short)r;
}
__device__ __forceinline__ unsigned cvtpk(float a, float b) {
    unsigned r;
    asm("v_cvt_pk_bf16_f32 %0, %1, %2" : "=v"(r) : "v"(a), "v"(b));
    return r;
}
__device__ __forceinline__ int pk4fp8(float a, float b, float c, float d) {
    int r = __builtin_amdgcn_cvt_pk_fp8_f32(a, b, 0, false);
    r = __builtin_amdgcn_cvt_pk_fp8_f32(c, d, r, true);
    return r;
}

__device__ __forceinline__ f32x4 mfma16(bf16x8 a, bf16x8 b, f32x4 c) {
    return __builtin_amdgcn_mfma_f32_16x16x32_bf16(a, b, c, 0, 0, 0);
}
__device__ __forceinline__ f32x4 mfma8(fp8x8 a, fp8x8 b, f32x4 c) {
    return __builtin_amdgcn_mfma_f32_16x16x32_fp8_fp8(a, b, c, 0, 0, 0);
}

__device__ __forceinline__ float sigmoidf_(float x) { return 1.f / (1.f + __expf(-x)); }
__device__ __forceinline__ float tanhf_(float x)    { return 2.f / (1.f + __expf(-2.f * x)) - 1.f; }
__device__ __forceinline__ float softplusf_(float x){ return (x > 20.f) ? x : __logf(1.f + __expf(x)); }

template<int IMM>
__device__ __forceinline__ bf16x8 gload(const short* sbase, unsigned voff) {
    bf16x8 d;
    if constexpr (IMM == 0) {
        asm volatile("global_load_dwordx4 %0, %1, %2" : "=v"(d) : "v"(voff), "s"(sbase));
    } else {
        asm volatile("global_load_dwordx4 %0, %1, %2 offset:%3"
                     : "=v"(d) : "v"(voff), "s"(sbase), "i"(IMM));
    }
    return d;
}
template<int IMM>
__device__ __forceinline__ fp8x8 gload8(const char* sbase, unsigned voff) {
    fp8x8 d;
    if constexpr (IMM == 0) {
        asm volatile("global_load_dwordx2 %0, %1, %2" : "=v"(d) : "v"(voff), "s"(sbase));
    } else {
        asm volatile("global_load_dwordx2 %0, %1, %2 offset:%3"
                     : "=v"(d) : "v"(voff), "s"(sbase), "i"(IMM));
    }
    return d;
}
__device__ __forceinline__ f32x2 gload2f(const float* sbase, unsigned voff) {
    f32x2 d;
    asm volatile("global_load_dwordx2 %0, %1, %2 nt" : "=v"(d) : "v"(voff), "s"(sbase));
    return d;
}
__device__ __forceinline__ float gload1f(const float* sbase, unsigned voff) {
    float d;
    asm volatile("global_load_dword %0, %1, %2 nt" : "=v"(d) : "v"(voff), "s"(sbase));
    return d;
}
__device__ __forceinline__ void gstore4f(float* sbase, unsigned voff, f32x4 v) {
    asm volatile("global_store_dwordx4 %0, %1, %2 nt" :: "v"(voff), "v"(v), "s"(sbase));
}
__device__ __forceinline__ void gstore1f(float* sbase, unsigned voff, float v) {
    asm volatile("global_store_dword %0, %1, %2 nt" :: "v"(voff), "v"(v), "s"(sbase));
}

#define VMW(N) do { asm volatile("s_waitcnt vmcnt(" #N ")" ::: "memory"); \
                    __builtin_amdgcn_sched_barrier(0); } while (0)
#define BAR() do { asm volatile("s_waitcnt lgkmcnt(0)" ::: "memory"); \
                   __builtin_amdgcn_s_barrier(); \
                   __builtin_amdgcn_sched_barrier(0); } while (0)

// ---------------------------------------------------------------------------
__global__ void pack_w_kernel(const float* __restrict__ W, short* __restrict__ dst,
                              int KT, int rowOff, int srcN, int total) {
    int tid = blockIdx.x * 256 + threadIdx.x;
    if (tid >= total) return;
    int j    = tid & 7;
    int lane = (tid >> 3) & 63;
    int kt   = (tid >> 9) % KT;
    int nt   = (tid >> 9) / KT;
    int k = kt * 32 + (lane >> 4) * 8 + j;
    int n = nt * 16 + (lane & 15);
    dst[tid] = f2bf(W[(size_t)(rowOff + k) * srcN + n]);
}

__global__ void pack_f8_kernel(const float* __restrict__ W, char* __restrict__ dst,
                               int KT, int rowOff, int colOff, int srcN, int total) {
    int tid = blockIdx.x * 256 + threadIdx.x;
    if (tid >= total) return;
    int j    = tid & 7;
    int lane = (tid >> 3) & 63;
    int kt   = (tid >> 9) % KT;
    int nt   = (tid >> 9) / KT;
    int k = kt * 32 + (lane >> 4) * 8 + j;
    int n = colOff + nt * 16 + (lane & 15);
    float v = W[(size_t)(rowOff + k) * srcN + n];
    int p = __builtin_amdgcn_cvt_pk_fp8_f32(v, 0.f, 0, false);
    dst[tid] = (char)(p & 0xFF);
}

__global__ void act_proj_kernel(const float* __restrict__ emb, const float* __restrict__ w_in,
                                const float* __restrict__ b_in, float* __restrict__ actp) {
    int c = threadIdx.x;
    int a = blockIdx.x;
    float s = b_in[c];
    for (int i = 0; i < AD_; ++i) s += emb[a * AD_ + i] * w_in[(SD_ + i) * HD_ + c];
    actp[a * HD_ + c] = s;
}

// ---------------------------------------------------------------------------
#define RPB 16
#define NTH 1024

struct WB { fp8x8 ri, ui, ni, rh, uh, nh; };   // 12 VGPR

template<int KT>
__device__ __forceinline__ void issueK(WB& b,
        const char* s8ri, const char* s8ui, const char* s8ni,
        const char* s8rh, const char* s8uh, const char* s8nh, unsigned voff8) {
    constexpr int IMM8 = KT * 512;
    b.ri = gload8<IMM8>(s8ri, voff8);
    b.ui = gload8<IMM8>(s8ui, voff8);
    b.ni = gload8<IMM8>(s8ni, voff8);
    b.rh = gload8<IMM8>(s8rh, voff8);
    b.uh = gload8<IMM8>(s8uh, voff8);
    b.nh = gload8<IMM8>(s8nh, voff8);
}

__launch_bounds__(NTH, 4)
__global__ void scan_kernel(const int* __restrict__ actions, const float* __restrict__ obs,
                            const float* __restrict__ noise,
                            const float* __restrict__ b_ih, const float* __restrict__ b_hh,
                            const float* __restrict__ g_ln, const float* __restrict__ beta_ln,
                            const float* __restrict__ b_q1, const float* __restrict__ b_q2,
                            const short* __restrict__ wpk, const char* __restrict__ w8,
                            const float* __restrict__ actp,
                            float* __restrict__ dscr, float* __restrict__ out) {
    __shared__ __align__(16) float ps_s [16][20];
    __shared__ __align__(16) float ps_ss[16][20];
    __shared__ __align__(16) float q2p[2][16][132];
    __shared__ __align__(16) char  xF8 [4096];
    __shared__ __align__(16) char  h8a [4096];
    __shared__ __align__(16) char  h8b [4096];
    __shared__ __align__(16) short q1F [4096];
    __shared__ __align__(16) short zF  [1024];
    __shared__ __align__(16) short obsF[2048];
    __shared__ __align__(16) float bsr_l[256], bsu_l[256], bin_l[256], bhn_l[256];
    __shared__ __align__(16) float bq1_l[256], lng_l[256], lnb_l[256], bq2_l[128];
    __shared__ __align__(16) unsigned char act8_l[L_][16];
    __shared__ __align__(16) float actp_l[NA_][260];

    const int tid  = threadIdx.x;
    const int w    = tid >> 6;
    const int lane = tid & 63;
    const int lrow = lane & 15;
    const int lgrp = lane >> 4;
    const int row0 = blockIdx.x * RPB;
    const int c0   = w * 16 + lgrp * 4;
    const int foff = lane * 8;          // shorts
    const int b8off = lane * 8;         // bytes
    const int fwb  = (c0 >> 5) * 512 + (lrow + 16 * ((c0 >> 3) & 3)) * 8 + (c0 & 7);
    const f32x4 zero4 = {0.f, 0.f, 0.f, 0.f};

    const int wu = __builtin_amdgcn_readfirstlane(w);
    const unsigned voff16 = (unsigned)lane * 16u;
    const unsigned voff8  = (unsigned)lane * 8u;
    const short* sbwz = wpk + OFF_WZ + (wu * 2) * 512;
    const char* s8ri  = w8 + W8_IHR + (wu * 8) * 512;
    const char* s8ui  = w8 + W8_IHU + (wu * 8) * 512;
    const char* s8ni  = w8 + W8_IHN + (wu * 8) * 512;
    const char* s8rh  = w8 + W8_HHR + (wu * 8) * 512;
    const char* s8uh  = w8 + W8_HHU + (wu * 8) * 512;
    const char* s8nh  = w8 + W8_HHN + (wu * 8) * 512;
    const char* s8q1h = w8 + W8_Q1H + (wu * 8) * 512;
    const short* sbq1w = wpk + OFF_WQ1W + (wu * 4) * 512;
    const int khalf = wu >> 3;
    const short* sbq2 = wpk + OFF_WQ2 + ((wu & 7) * 8 + khalf * 4) * 512;

    // Wq1w register-resident (bf16, nt=w)
    const bf16x8 Wq1w0 = *(const bf16x8*)&sbq1w[0 * 512 + foff];
    const bf16x8 Wq1w1 = *(const bf16x8*)&sbq1w[1 * 512 + foff];
    const bf16x8 Wq1w2 = *(const bf16x8*)&sbq1w[2 * 512 + foff];
    const bf16x8 Wq1w3 = *(const bf16x8*)&sbq1w[3 * 512 + foff];
    asm volatile("" :: "v"(Wq1w0), "v"(Wq1w1), "v"(Wq1w2), "v"(Wq1w3));  // pin

    // prologue: params/actions/actp -> LDS; zero state
    if (tid < 256) {
        bsr_l[tid] = b_ih[tid] + b_hh[tid];
        bsu_l[tid] = b_ih[256 + tid] + b_hh[256 + tid];
        bin_l[tid] = b_ih[512 + tid];
        bhn_l[tid] = b_hh[512 + tid];
        bq1_l[tid] = b_q1[tid];
        lng_l[tid] = g_ln[tid];
        lnb_l[tid] = beta_ln[tid];
    } else if (tid < 384) {
        bq2_l[tid - 256] = b_q2[tid - 256];
    }
    for (int i = tid; i < RPB * L_; i += NTH) {
        int r = i >> 8, tt = i & 255;
        act8_l[tt][r] = (unsigned char)actions[(row0 + r) * L_ + tt];
    }
    for (int i = tid; i < NA_ * HD_; i += NTH)
        actp_l[i >> 8][i & 255] = actp[i];
    for (int i = tid; i < 4096; i += NTH) h8a[i] = 0;
    for (int i = tid; i < 1024; i += NTH) zF[i] = 0;
    f32x4 hreg = zero4;

    unsigned obs_off = (unsigned)((row0 + w) * L_) * (WD_ * 4u) + (unsigned)lane * 8u;
    unsigned nz_off  = (unsigned)((row0 + w) * L_) * (SD_ * 4u) + (unsigned)lane * 4u;
    unsigned ho_off  = (unsigned)((row0 + lrow) * L_) * (OUT_ * 4u) + (unsigned)c0 * 4u;
    unsigned zo_off  = (unsigned)((row0 + w) * L_) * (OUT_ * 4u);
    __syncthreads();   // drains prologue VMEM; ledger starts at 0

    WB w0, w1, w2;
    fp8x8 db0, db1, db2, db3, db4, db5, db6, db7;
    bf16x8 eb0, eb1, eb2, eb3;
    bf16x8 wzb0, wzb1;
    f32x2 obsv, obsv_n;
    float nzv, nzv_n;

    // BOOTSTRAP: [obs nz Wz(2) K0 K1 K2]=22; VMW(20) -> obs,nz done; st4 -> 24
    obsv = gload2f(obs, obs_off);
    nzv  = gload1f(noise, nz_off);
    wzb0 = gload<0>   (sbwz, voff16);
    wzb1 = gload<1024>(sbwz, voff16);
    issueK<0>(w0, s8ri, s8ui, s8ni, s8rh, s8uh, s8nh, voff8);
    issueK<1>(w1, s8ri, s8ui, s8ni, s8rh, s8uh, s8nh, voff8);
    issueK<2>(w2, s8ri, s8ui, s8ni, s8rh, s8uh, s8nh, voff8);
    VMW(20);
    {
        unsigned doff = (unsigned)tid * 16u;
        gstore4f(dscr, doff, zero4);
        gstore4f(dscr, doff + 16384u, zero4);
        gstore4f(dscr, doff + 32768u, zero4);
        gstore4f(dscr, doff + 49152u, zero4);
    }

    for (int t = 0; t < L_; ++t) {
        const char* h8c = (t & 1) ? h8b : h8a;   // read in B
        char*       h8n = (t & 1) ? h8a : h8b;   // written in C, read in D

        // ---- Phase A: xpre = z@Wz + actp[act]; LN partials; obsF stage ------
        f32x4 xp;
        {
            VMW(22);   // Wz pair complete ([K0-2 st4]=22 behind)
            f32x4 a = zero4;
            a = mfma16(wzb0, *(const bf16x8*)&zF[foff], a);
            a = mfma16(wzb1, *(const bf16x8*)&zF[512 + foff], a);
            int act = act8_l[t][lrow];
            xp = a + *(const f32x4*)&actp_l[act][c0];
            float s  = xp[0] + xp[1] + xp[2] + xp[3];
            float ss = xp[0]*xp[0] + xp[1]*xp[1] + xp[2]*xp[2] + xp[3]*xp[3];
            s  += __shfl_xor(s, 16, 64);  s  += __shfl_xor(s, 32, 64);
            ss += __shfl_xor(ss, 16, 64); ss += __shfl_xor(ss, 32, 64);
            if (lgrp == 0) { ps_s[lrow][w] = s; ps_ss[lrow][w] = ss; }
            // obs -> obsF bf16 (wave w = row w; 2 shorts per lane)
            int oc = lane * 2;
            *(unsigned*)&obsF[(oc >> 5) * 512 + (w + 16 * ((oc >> 3) & 3)) * 8 + (oc & 7)]
                = cvtpk(obsv[0], obsv[1]);
        }
        BAR();   // (1)

        // ---- LN finish + xF8 (fp8 only) --------------------------------------
        {
            float s  = ps_s [lrow][lgrp] + ps_s [lrow][lgrp + 4]
                     + ps_s [lrow][lgrp + 8] + ps_s [lrow][lgrp + 12];
            float ss = ps_ss[lrow][lgrp] + ps_ss[lrow][lgrp + 4]
                     + ps_ss[lrow][lgrp + 8] + ps_ss[lrow][lgrp + 12];
            s  += __shfl_xor(s, 16, 64);  s  += __shfl_xor(s, 32, 64);
            ss += __shfl_xor(ss, 16, 64); ss += __shfl_xor(ss, 32, 64);
            float mean = s * (1.f / 256.f);
            float rstd = rsqrtf(ss * (1.f / 256.f) - mean * mean + 1e-5f);
            f32x4 g  = *(const f32x4*)&lng_l[c0];
            f32x4 bb = *(const f32x4*)&lnb_l[c0];
            float r0 = fmaxf((xp[0] - mean) * rstd * g[0] + bb[0], 0.f);
            float r1 = fmaxf((xp[1] - mean) * rstd * g[1] + bb[1], 0.f);
            float r2 = fmaxf((xp[2] - mean) * rstd * g[2] + bb[2], 0.f);
            float r3 = fmaxf((xp[3] - mean) * rstd * g[3] + bb[3], 0.f);
            *(int*)&xF8[fwb] = pk4fp8(r0, r1, r2, r3);
        }
        BAR();   // (2)

        // ---- Phase B: GRU all-fp8, 3-slot-deep pipeline ----------------------
        f32x4 ar = zero4, au = zero4, aI = zero4, aH = zero4;
#define SLOT(KT, WBUF) { \
        fp8x8 x8 = *(const fp8x8*)&xF8[(KT) * 512 + b8off]; \
        fp8x8 h8 = *(const fp8x8*)&h8c[(KT) * 512 + b8off]; \
        ar = mfma8(WBUF.ri, x8, ar); ar = mfma8(WBUF.rh, h8, ar); \
        au = mfma8(WBUF.ui, x8, au); au = mfma8(WBUF.uh, h8, au); \
        aI = mfma8(WBUF.ni, x8, aI); aH = mfma8(WBUF.nh, h8, aH); }
#define ISSUE(KT, W) issueK<KT>(W, s8ri, s8ui, s8ni, s8rh, s8uh, s8nh, voff8)

        VMW(16); SLOT(0, w0) ISSUE(3, w0);
        VMW(16); SLOT(1, w1) ISSUE(4, w1);
        VMW(16); SLOT(2, w2) ISSUE(5, w2);
        VMW(12); SLOT(3, w0) ISSUE(6, w0);
        VMW(12); SLOT(4, w1) ISSUE(7, w1);
        VMW(12); SLOT(5, w2)
        db0 = gload8<0>   (s8q1h, voff8);
        db1 = gload8<512> (s8q1h, voff8);
        db2 = gload8<1024>(s8q1h, voff8);
        db3 = gload8<1536>(s8q1h, voff8);
        VMW(10); SLOT(6, w0)
        db4 = gload8<2048>(s8q1h, voff8);
        db5 = gload8<2560>(s8q1h, voff8);
        db6 = gload8<3072>(s8q1h, voff8);
        db7 = gload8<3584>(s8q1h, voff8);
        VMW(8);  SLOT(7, w1)
        eb0 = gload<0>   (sbq2, voff16);
        eb1 = gload<1024>(sbq2, voff16);
        eb2 = gload<2048>(sbq2, voff16);
        eb3 = gload<3072>(sbq2, voff16);
        {
            unsigned onext = obs_off + ((t < L_ - 1) ? (WD_ * 4u) : 0u);
            unsigned nnext = nz_off  + ((t < L_ - 1) ? (SD_ * 4u) : 0u);
            obsv_n = gload2f(obs, onext);
            nzv_n  = gload1f(noise, nnext);
            obs_off = onext; nz_off = nnext;
        }
#undef SLOT
#undef ISSUE
        // (no barrier: C writes the other h buffer)

        // ---- Phase C: gates (VALU), write h8n --------------------------------
        {
            f32x4 bsr = *(const f32x4*)&bsr_l[c0];
            f32x4 bsu = *(const f32x4*)&bsu_l[c0];
            f32x4 bin = *(const f32x4*)&bin_l[c0];
            f32x4 bhn = *(const f32x4*)&bhn_l[c0];
            f32x4 hv;
            #pragma unroll
            for (int j = 0; j < 4; ++j) {
                float rr = sigmoidf_(ar[j] + bsr[j]);
                float uu = sigmoidf_(au[j] + bsu[j]);
                float nn = tanhf_(aI[j] + bin[j] + rr * (aH[j] + bhn[j]));
                hv[j] = (1.f - uu) * nn + uu * hreg[j];
            }
            hreg = hv;
            *(int*)&h8n[fwb] = pk4fp8(hv[0], hv[1], hv[2], hv[3]);
        }
        BAR();   // (4)

        // ---- Phase D: q1 = relu(h@Wq1h[fp8] + obs@Wq1w[bf16] + b_q1) ---------
        {
            f32x4 aq = zero4;
            fp8x8 t0 = *(const fp8x8*)&h8n[0 * 512 + b8off];
            fp8x8 t1 = *(const fp8x8*)&h8n[1 * 512 + b8off];
            fp8x8 t2 = *(const fp8x8*)&h8n[2 * 512 + b8off];
            fp8x8 t3 = *(const fp8x8*)&h8n[3 * 512 + b8off];
            VMW(10);   // db0-3 ready
            aq = mfma8(db0, t0, aq); aq = mfma8(db1, t1, aq);
            aq = mfma8(db2, t2, aq); aq = mfma8(db3, t3, aq);
            fp8x8 t4 = *(const fp8x8*)&h8n[4 * 512 + b8off];
            fp8x8 t5 = *(const fp8x8*)&h8n[5 * 512 + b8off];
            fp8x8 t6 = *(const fp8x8*)&h8n[6 * 512 + b8off];
            fp8x8 t7 = *(const fp8x8*)&h8n[7 * 512 + b8off];
            VMW(6);    // db4-7 ready
            aq = mfma8(db4, t4, aq); aq = mfma8(db5, t5, aq);
            aq = mfma8(db6, t6, aq); aq = mfma8(db7, t7, aq);
            // issue NEXT step stream: Wz'(2), K0-2'(18)
            wzb0 = gload<0>   (sbwz, voff16);
            wzb1 = gload<1024>(sbwz, voff16);
            issueK<0>(w0, s8ri, s8ui, s8ni, s8rh, s8uh, s8nh, voff8);
            issueK<1>(w1, s8ri, s8ui, s8ni, s8rh, s8uh, s8nh, voff8);
            issueK<2>(w2, s8ri, s8ui, s8ni, s8rh, s8uh, s8nh, voff8);
            // obs part (register bf16 weights, LDS obsF)
            bf16x8 o0 = *(const bf16x8*)&obsF[0 * 512 + foff];
            bf16x8 o1 = *(const bf16x8*)&obsF[1 * 512 + foff];
            bf16x8 o2 = *(const bf16x8*)&obsF[2 * 512 + foff];
            bf16x8 o3 = *(const bf16x8*)&obsF[3 * 512 + foff];
            aq = mfma16(Wq1w0, o0, aq); aq = mfma16(Wq1w1, o1, aq);
            aq = mfma16(Wq1w2, o2, aq); aq = mfma16(Wq1w3, o3, aq);
            f32x4 bq = *(const f32x4*)&bq1_l[c0];
            u32x2 qb;
            qb[0] = cvtpk(fmaxf(aq[0] + bq[0], 0.f), fmaxf(aq[1] + bq[1], 0.f));
            qb[1] = cvtpk(fmaxf(aq[2] + bq[2], 0.f), fmaxf(aq[3] + bq[3], 0.f));
            *(u32x2*)&q1F[fwb] = qb;
        }
        BAR();   // (5)

        // ---- Phase E: q2 partials (streamed bf16 eb, C+D lead) ---------------
        {
            f32x4 a = zero4;
            VMW(22);   // eb done; [obs' nz' Wz' K0-2'] = 22 behind
            bf16x8 q0 = *(const bf16x8*)&q1F[(khalf * 4 + 0) * 512 + foff];
            bf16x8 q1 = *(const bf16x8*)&q1F[(khalf * 4 + 1) * 512 + foff];
            bf16x8 q2 = *(const bf16x8*)&q1F[(khalf * 4 + 2) * 512 + foff];
            bf16x8 q3 = *(const bf16x8*)&q1F[(khalf * 4 + 3) * 512 + foff];
            a = mfma16(eb0, q0, a); a = mfma16(eb1, q1, a);
            a = mfma16(eb2, q2, a); a = mfma16(eb3, q3, a);
            *(f32x4*)&q2p[khalf][lrow][(wu & 7) * 16 + lgrp * 4] = a;
        }
        BAR();   // (6)

        // ---- Phase F: z sample; zF; counted out-stores -----------------------
        {
            int n = lane;   // wave w = row w
            VMW(20);        // obs',nz' done; [Wz' K0-2'] = 20 behind
            float qm = q2p[0][w][n]      + q2p[1][w][n]      + bq2_l[n];
            float ql = q2p[0][w][64 + n] + q2p[1][w][64 + n] + bq2_l[64 + n];
            float qs = softplusf_(ql) + 0.1f;
            float zv = qm + qs * nzv;
            zF[(n >> 5) * 512 + (w + 16 * ((n >> 3) & 3)) * 8 + (n & 7)] = f2bf(zv);
            unsigned zo = zo_off;
            gstore4f(out, ho_off, hreg);
            gstore1f(out, zo + (256 + n) * 4u, zv);
            gstore1f(out, zo + (448 + n) * 4u, qm);
            gstore1f(out, zo + (512 + n) * 4u, qs);
            obsv = obsv_n;
            nzv  = nzv_n;
        }
        BAR();   // (7)
        ho_off += OUT_ * 4u;
        zo_off += OUT_ * 4u;
    }
    asm volatile("s_waitcnt vmcnt(0)" ::: "memory");
}

// ---------------------------------------------------------------------------
__launch_bounds__(256, 2)
__global__ void prior_kernel(const float* __restrict__ b_p1, const float* __restrict__ b_p2,
                             const short* __restrict__ wpk, float* __restrict__ out) {
    const short* wp1 = wpk + OFF_WP1;
    const short* wp2 = wpk + OFF_WP2;
    __shared__ __align__(16) short p1b[4][16][264];
    const int tid = threadIdx.x, wid = tid >> 6, lane = tid & 63;
    const int lrow = lane & 15, lgrp = lane >> 4;
    const size_t rbase = (size_t)blockIdx.x * 64 + wid * 16;
    const f32x4 zero4 = {0.f, 0.f, 0.f, 0.f};

    f32x4 acc[16];
    #pragma unroll
    for (int nt = 0; nt < 16; ++nt) acc[nt] = zero4;
    for (int kt = 0; kt < 8; ++kt) {
        const f32x4* hp = (const f32x4*)&out[(rbase + lrow) * OUT_ + kt * 32 + lgrp * 8];
        f32x4 h0 = hp[0], h1 = hp[1];
        bf16x8 a;
        a[0] = f2bf(h0[0]); a[1] = f2bf(h0[1]); a[2] = f2bf(h0[2]); a[3] = f2bf(h0[3]);
        a[4] = f2bf(h1[0]); a[5] = f2bf(h1[1]); a[6] = f2bf(h1[2]); a[7] = f2bf(h1[3]);
        #pragma unroll
        for (int nt = 0; nt < 16; ++nt) {
            bf16x8 b = *(const bf16x8*)&wp1[(nt * 8 + kt) * 512 + lane * 8];
            acc[nt] = mfma16(a, b, acc[nt]);
        }
    }
    #pragma unroll
    for (int nt = 0; nt < 16; ++nt) {
        int colb = nt * 16 + lrow;
        #pragma unroll
        for (int j = 0; j < 4; ++j)
            p1b[wid][lgrp * 4 + j][colb] = f2bf(fmaxf(acc[nt][j] + b_p1[colb], 0.f));
    }
    __syncthreads();

    f32x4 acc2[8];
    #pragma unroll
    for (int nt = 0; nt < 8; ++nt) acc2[nt] = zero4;
    for (int kt = 0; kt < 8; ++kt) {
        bf16x8 a = *(const bf16x8*)&p1b[wid][lrow][kt * 32 + lgrp * 8];
        #pragma unroll
        for (int nt = 0; nt < 8; ++nt) {
            bf16x8 b = *(const bf16x8*)&wp2[(nt * 8 + kt) * 512 + lane * 8];
            acc2[nt] = mfma16(a, b, acc2[nt]);
        }
    }
    #pragma unroll
    for (int nt = 0; nt < 8; ++nt) {
        #pragma unroll
        for (int j = 0; j < 4; ++j) {
            size_t rw = rbase + lgrp * 4 + j;
            int col = nt * 16 + lrow;
            float v = acc2[nt][j] + b_p2[col];
            if (col < 64) out[rw * OUT_ + 320 + col] = v;
            else          out[rw * OUT_ + 384 + (col - 64)] = softplusf_(v) + 0.1f;
        }
    }
}

// ---------------------------------------------------------------------------
extern "C" void kernel_launch(void* const* d_in, const int* in_sizes, int n_in,
                              void* d_out, int out_size, void* d_ws, size_t ws_size,
                              hipStream_t stream) {
    const int*   actions = (const int*)  d_in[0];
    const float* obs     = (const float*)d_in[1];
    const float* noise   = (const float*)d_in[2];
    const float* emb     = (const float*)d_in[3];
    const float* w_in    = (const float*)d_in[4];
    const float* b_in    = (const float*)d_in[5];
    const float* g_ln    = (const float*)d_in[6];
    const float* beta_ln = (const float*)d_in[7];
    const float* w_ih    = (const float*)d_in[8];
    const float* b_ih    = (const float*)d_in[9];
    const float* w_hh    = (const float*)d_in[10];
    const float* b_hh    = (const float*)d_in[11];
    const float* w_p1    = (const float*)d_in[12];
    const float* b_p1    = (const float*)d_in[13];
    const float* w_p2    = (const float*)d_in[14];
    const float* b_p2    = (const float*)d_in[15];
    const float* w_q1    = (const float*)d_in[16];
    const float* b_q1    = (const float*)d_in[17];
    const float* w_q2    = (const float*)d_in[18];
    const float* b_q2    = (const float*)d_in[19];

    short* wpk  = (short*)d_ws;
    float* actp = (float*)((char*)d_ws + OFF_ACTP_BYTES);
    float* dscr = (float*)((char*)d_ws + OFF_DSCR_BYTES);
    char*  w8   = (char*) d_ws + OFF_W8_BYTES;
    float* out  = (float*)d_out;

    auto packLaunch = [&](const float* W, int off, int KT, int rowOff, int srcN, int total) {
        pack_w_kernel<<<(total + 255) / 256, 256, 0, stream>>>(W, wpk + off, KT, rowOff, srcN, total);
    };
    packLaunch(w_in, OFF_WZ,    2, 0,   256, 64 * 256);
    packLaunch(w_q1, OFF_WQ1W,  4, 256, 256, 128 * 256);
    packLaunch(w_q2, OFF_WQ2,   8, 0,   128, 256 * 128);
    packLaunch(w_p1, OFF_WP1,   8, 0,   256, 256 * 256);
    packLaunch(w_p2, OFF_WP2,   8, 0,   128, 256 * 128);

    auto pack8 = [&](const float* W, int dstOff, int colOff, int srcN) {
        pack_f8_kernel<<<256, 256, 0, stream>>>(W, w8 + dstOff, 8, 0, colOff, srcN, 65536);
    };
    pack8(w_ih, W8_IHR, 0,   768);
    pack8(w_ih, W8_IHU, 256, 768);
    pack8(w_ih, W8_IHN, 512, 768);
    pack8(w_hh, W8_HHR, 0,   768);
    pack8(w_hh, W8_HHU, 256, 768);
    pack8(w_hh, W8_HHN, 512, 768);
    pack8(w_q1, W8_Q1H, 0,   256);
    act_proj_kernel<<<NA_, 256, 0, stream>>>(emb, w_in, b_in, actp);

    scan_kernel<<<B_ / RPB, NTH, 0, stream>>>(actions, obs, noise, b_ih, b_hh,
                                              g_ln, beta_ln, b_q1, b_q2, wpk, w8, actp, dscr, out);
    prior_kernel<<<(B_ * L_) / 64, 256, 0, stream>>>(b_p1, b_p2, wpk, out);
}